// Round 1
// baseline (1922.712 us; speedup 1.0000x reference)
//
#include <hip/hip_runtime.h>
#include <hip/hip_bf16.h>

typedef unsigned short u16;
typedef unsigned int u32;
typedef unsigned long long u64;
typedef __attribute__((ext_vector_type(8))) short s16x8;
typedef __attribute__((ext_vector_type(8))) unsigned short u16x8;
typedef __attribute__((ext_vector_type(4))) float fx4;
typedef __attribute__((ext_vector_type(4))) unsigned int ux4;

__device__ __forceinline__ float bf2f(u16 u){ u32 x=((u32)u)<<16; return __builtin_bit_cast(float,x); }
__device__ __forceinline__ u16 f2bf(float f){ u32 x=__builtin_bit_cast(u32,f); return (u16)((x + 0x7FFFu + ((x>>16)&1u))>>16); }

__device__ __forceinline__ u64 spread3(u32 v){
  u64 x = v & 0xFFFFull;
  x = (x | (x<<32)) & 0x001f00000000ffffull;
  x = (x | (x<<16)) & 0x001f0000ff0000ffull;
  x = (x | (x<<8))  & 0x100f00f00f00f00full;
  x = (x | (x<<4))  & 0x10c30c30c30c30c3ull;
  x = (x | (x<<2))  & 0x1249249249249249ull;
  return x;
}

// ---------------- Morton sort (single block, bitonic in LDS) ----------------
__global__ __launch_bounds__(1024) void sort_kernel(const float* __restrict__ xyz,
        int* __restrict__ order, int* __restrict__ gridS, int N)
{
  extern __shared__ char dsm[];
  u64* keys = (u64*)dsm;
  __shared__ float red[3][16];
  __shared__ float mnS[3];
  int t = threadIdx.x; int lane = t&63; int wv = t>>6;
  float m0=3.4e38f,m1=3.4e38f,m2=3.4e38f;
  for (int i=t;i<N;i+=1024){
    m0=fminf(m0,xyz[i]); m1=fminf(m1,xyz[N+i]); m2=fminf(m2,xyz[2*N+i]);
  }
  for (int s=1;s<64;s<<=1){
    m0=fminf(m0,__shfl_xor(m0,s));
    m1=fminf(m1,__shfl_xor(m1,s));
    m2=fminf(m2,__shfl_xor(m2,s));
  }
  if (lane==0){ red[0][wv]=m0; red[1][wv]=m1; red[2][wv]=m2; }
  __syncthreads();
  if (t<3){ float m=red[t][0]; for(int i=1;i<16;i++) m=fminf(m,red[t][i]); mnS[t]=m; }
  __syncthreads();
  float mx0=mnS[0],mx1=mnS[1],mx2=mnS[2];
  for (int i=t;i<N;i+=1024){
    int gx=(int)((xyz[i]-mx0)/0.02f);     gx = gx<0?0:(gx>65535?65535:gx);
    int gy=(int)((xyz[N+i]-mx1)/0.02f);   gy = gy<0?0:(gy>65535?65535:gy);
    int gz=(int)((xyz[2*N+i]-mx2)/0.02f); gz = gz<0?0:(gz>65535?65535:gz);
    u64 mort = (spread3((u32)gx)<<2)|(spread3((u32)gy)<<1)|spread3((u32)gz);
    keys[i] = (mort<<14) | (u64)i;   // stable tie-break = ascending index
  }
  for (int size=2; size<=N; size<<=1){
    for (int stride=size>>1; stride>0; stride>>=1){
      __syncthreads();
      for (int p=t;p<(N>>1);p+=1024){
        int i = 2*p - (p & (stride-1));
        int j = i + stride;
        u64 a=keys[i], bk=keys[j];
        bool up = ((i & size)==0);
        if ((a>bk)==up){ keys[i]=bk; keys[j]=a; }
      }
    }
  }
  __syncthreads();
  for (int i=t;i<N;i+=1024){
    int orig = (int)(keys[i] & 16383ull);
    order[i] = orig;
    int gx=(int)((xyz[orig]-mx0)/0.02f);     gx = gx<0?0:(gx>65535?65535:gx);
    int gy=(int)((xyz[N+orig]-mx1)/0.02f);   gy = gy<0?0:(gy>65535?65535:gy);
    int gz=(int)((xyz[2*N+orig]-mx2)/0.02f); gz = gz<0?0:(gz>65535?65535:gz);
    gridS[i*3+0]=gx; gridS[i*3+1]=gy; gridS[i*3+2]=gz;
  }
}

// ---------------- weight transpose -> bf16 (Nout, K) ----------------
__global__ __launch_bounds__(256) void wtrans_kernel(const float* __restrict__ W, u16* __restrict__ Wt, int K, int Nc)
{
  __shared__ float tl[32][33];
  int nb = Nc/32;
  int n0 = (blockIdx.x % nb)*32;
  int k0 = (blockIdx.x / nb)*32;
  int t=threadIdx.x; int r=t>>5, c=t&31;
  #pragma unroll
  for (int p=0;p<4;p++) tl[p*8+r][c] = W[(size_t)(k0+p*8+r)*Nc + n0+c];
  __syncthreads();
  #pragma unroll
  for (int p=0;p<4;p++) Wt[(size_t)(n0+p*8+r)*K + k0+c] = f2bf(tl[c][p*8+r]);
}

// ---------------- LN1 fused with (C,N)->(N,C) transpose ----------------
__global__ __launch_bounds__(256) void ln1_kernel(const float* __restrict__ x, const float* __restrict__ g,
     const float* __restrict__ b, u16* __restrict__ xn, int N)
{
  extern __shared__ char dsm[];
  float* tile = (float*)dsm; // [64][388]
  int n0 = blockIdx.x*64;
  int t = threadIdx.x;
  #pragma unroll 4
  for (int p=0;p<96;p++){
    int cc = p*4 + (t>>6);
    tile[(t&63)*388 + cc] = x[(size_t)cc*N + n0 + (t&63)];
  }
  __syncthreads();
  int tok = t>>2, part = t&3;
  const float* row = tile + tok*388 + part*96;
  float s=0.f;
  #pragma unroll
  for (int j=0;j<96;j++) s += row[j];
  s += __shfl_xor(s,1); s += __shfl_xor(s,2);
  float mu = s*(1.0f/384.0f);
  float vr=0.f;
  #pragma unroll
  for (int j=0;j<96;j++){ float d=row[j]-mu; vr += d*d; }
  vr += __shfl_xor(vr,1); vr += __shfl_xor(vr,2);
  float rs = rsqrtf(vr*(1.0f/384.0f) + 1e-5f);
  u16* dst = xn + (size_t)(n0+tok)*384 + part*96;
  #pragma unroll
  for (int q=0;q<12;q++){
    u16x8 o;
    #pragma unroll
    for (int j=0;j<8;j++){
      int c = part*96 + q*8 + j;
      o[j] = f2bf((row[q*8+j]-mu)*rs*g[c] + b[c]);
    }
    *(u16x8*)(dst + q*8) = o;
  }
}

// ---------------- generic bf16 MFMA GEMM with fused epilogues ----------------
__device__ __forceinline__ float gelu_f(float v){
  return 0.5f*v*(1.0f + erff(v*0.7071067811865475f));
}

// EPI 0: out bf16 = acc+bias          (QKV)
// EPI 1: out bf16 = gelu(acc+bias)    (FFN1)
// EPI 2: outF f32 = acc+bias+x^T      (proj, res = x (C,M))
// EPI 3: outF f32 (transposed store) = acc+bias+res (FFN2, res = y1 (M,Nout))
template<int EPI>
__global__ __launch_bounds__(256) void gemm_kernel(const u16* __restrict__ A, const u16* __restrict__ Bt,
    const float* __restrict__ bias, u16* __restrict__ outB, float* __restrict__ outF,
    const float* __restrict__ res, int M, int Nout, int K)
{
  __shared__ u16 Al[64][40];
  __shared__ u16 Bl[64][40];
  __shared__ float et[64][65];
  int nb = Nout>>6;
  int m0 = (blockIdx.x/nb)<<6;
  int n0 = (blockIdx.x%nb)<<6;
  int t = threadIdx.x, lane=t&63, wv=t>>6, wr=wv>>1, wc=wv&1;
  int lrow=t>>2, lcol=(t&3)<<3;
  fx4 acc[2][2];
  #pragma unroll
  for(int i=0;i<2;i++)
  #pragma unroll
  for(int j=0;j<2;j++) acc[i][j]=(fx4){0.f,0.f,0.f,0.f};
  const u16* Ap = A + (size_t)(m0+lrow)*K + lcol;
  const u16* Bp = Bt + (size_t)(n0+lrow)*K + lcol;
  int fr = lane&15, fk = (lane>>4)<<3;
  for (int k0=0;k0<K;k0+=32){
    *(ux4*)&Al[lrow][lcol] = *(const ux4*)(Ap+k0);
    *(ux4*)&Bl[lrow][lcol] = *(const ux4*)(Bp+k0);
    __syncthreads();
    s16x8 a0 = *(const s16x8*)&Al[wr*32+fr][fk];
    s16x8 a1 = *(const s16x8*)&Al[wr*32+16+fr][fk];
    s16x8 b0 = *(const s16x8*)&Bl[wc*32+fr][fk];
    s16x8 b1 = *(const s16x8*)&Bl[wc*32+16+fr][fk];
    acc[0][0] = __builtin_amdgcn_mfma_f32_16x16x32_bf16(a0,b0,acc[0][0],0,0,0);
    acc[0][1] = __builtin_amdgcn_mfma_f32_16x16x32_bf16(a0,b1,acc[0][1],0,0,0);
    acc[1][0] = __builtin_amdgcn_mfma_f32_16x16x32_bf16(a1,b0,acc[1][0],0,0,0);
    acc[1][1] = __builtin_amdgcn_mfma_f32_16x16x32_bf16(a1,b1,acc[1][1],0,0,0);
    __syncthreads();
  }
  int r0=(lane>>4)<<2;
  if (EPI==0 || EPI==1){
    #pragma unroll
    for (int mi=0;mi<2;mi++)
    #pragma unroll
    for (int ni=0;ni<2;ni++){
      int c = n0 + wc*32 + ni*16 + fr;
      float bi = bias[c];
      #pragma unroll
      for (int j=0;j<4;j++){
        int m = m0 + wr*32 + mi*16 + r0 + j;
        float vv = acc[mi][ni][j] + bi;
        if (EPI==1) vv = gelu_f(vv);
        outB[(size_t)m*Nout + c] = f2bf(vv);
      }
    }
  } else if (EPI==2){
    #pragma unroll
    for (int p=0;p<16;p++){
      int cc = p*4 + (t>>6);
      et[t&63][cc] = res[(size_t)(n0+cc)*M + m0 + (t&63)];
    }
    __syncthreads();
    #pragma unroll
    for (int mi=0;mi<2;mi++)
    #pragma unroll
    for (int ni=0;ni<2;ni++){
      int lc = wc*32 + ni*16 + fr;
      float bi = bias[n0+lc];
      #pragma unroll
      for (int j=0;j<4;j++){
        int lm = wr*32 + mi*16 + r0 + j;
        outF[(size_t)(m0+lm)*Nout + n0+lc] = acc[mi][ni][j] + bi + et[lm][lc];
      }
    }
  } else {
    #pragma unroll
    for (int mi=0;mi<2;mi++)
    #pragma unroll
    for (int ni=0;ni<2;ni++){
      int lc = wc*32 + ni*16 + fr;
      float bi = bias[n0+lc];
      #pragma unroll
      for (int j=0;j<4;j++){
        int lm = wr*32 + mi*16 + r0 + j;
        et[lm][lc] = acc[mi][ni][j] + bi + res[(size_t)(m0+lm)*Nout + n0+lc];
      }
    }
    __syncthreads();
    #pragma unroll
    for (int p=0;p<16;p++){
      int cc = p*4 + (t>>6);
      outF[(size_t)(n0+cc)*M + m0 + (t&63)] = et[t&63][cc];
    }
  }
}

// ---------------- RoPE + gather-into-sorted-window layout ----------------
__global__ __launch_bounds__(256) void rope_kernel(const u16* __restrict__ qkv, const int* __restrict__ order,
    const int* __restrict__ gridS, u16* __restrict__ Qp, u16* __restrict__ Kp, u16* __restrict__ Vp, int N)
{
  __shared__ float csm[64][24][2];
  __shared__ int origs[64];
  int i0 = blockIdx.x<<6;
  int t = threadIdx.x;
  if (t<64) origs[t] = order[i0+t];
  for (int idx=t; idx<64*24; idx+=256){
    int tok = idx/24, slot = idx - tok*24;
    int a = slot>>3, fi = slot&7;
    int pos = gridS[(size_t)(i0+tok)*3 + a];
    pos = pos<0?0:(pos>4095?4095:pos);
    float invf = powf(100.0f, -(float)fi*0.125f);
    float ang = (float)pos * invf;
    csm[tok][slot][0] = cosf(ang);
    csm[tok][slot][1] = sinf(ang);
  }
  __syncthreads();
  int tok = t&63;
  int i = i0 + tok;
  const u16* src = qkv + (size_t)origs[tok]*1152;
  u16x8 zz = {0,0,0,0,0,0,0,0};
  for (int h=t>>6; h<8; h+=4){
    size_t dst = ((size_t)h*N + i)*64;
    #pragma unroll
    for (int a=0;a<3;a++){
      u16x8 qa = *(const u16x8*)(src + h*48 + a*16);
      u16x8 qb = *(const u16x8*)(src + h*48 + a*16 + 8);
      u16x8 ka = *(const u16x8*)(src + 384 + h*48 + a*16);
      u16x8 kb = *(const u16x8*)(src + 384 + h*48 + a*16 + 8);
      u16x8 oqa, oqb, oka, okb;
      #pragma unroll
      for (int j=0;j<8;j++){
        float c0 = csm[tok][a*8+j][0], s0 = csm[tok][a*8+j][1];
        float ql = bf2f(qa[j]), qh = bf2f(qb[j]);
        float kl = bf2f(ka[j]), kh = bf2f(kb[j]);
        oqa[j] = f2bf(ql*c0 - qh*s0);
        oqb[j] = f2bf(qh*c0 + ql*s0);
        oka[j] = f2bf(kl*c0 - kh*s0);
        okb[j] = f2bf(kh*c0 + kl*s0);
      }
      *(u16x8*)(Qp + dst + a*16) = oqa;
      *(u16x8*)(Qp + dst + a*16 + 8) = oqb;
      *(u16x8*)(Kp + dst + a*16) = oka;
      *(u16x8*)(Kp + dst + a*16 + 8) = okb;
      u16x8 va = *(const u16x8*)(src + 768 + h*48 + a*16);
      u16x8 vb = *(const u16x8*)(src + 768 + h*48 + a*16 + 8);
      *(u16x8*)(Vp + dst + a*16) = va;
      *(u16x8*)(Vp + dst + a*16 + 8) = vb;
    }
    *(u16x8*)(Qp + dst + 48) = zz; *(u16x8*)(Qp + dst + 56) = zz;
    *(u16x8*)(Kp + dst + 48) = zz; *(u16x8*)(Kp + dst + 56) = zz;
    *(u16x8*)(Vp + dst + 48) = zz; *(u16x8*)(Vp + dst + 56) = zz;
  }
}

// ---------------- V transpose to (h, w, d64, k1024) ----------------
__global__ __launch_bounds__(256) void vtrans_kernel(const u16* __restrict__ Vp, u16* __restrict__ Vt, int N)
{
  __shared__ u16 tl[64][65];
  int nkb = N>>6;
  int h = blockIdx.x / nkb;
  int k0 = (blockIdx.x % nkb)<<6;
  int t=threadIdx.x;
  #pragma unroll
  for (int p=0;p<16;p++){
    int rr = p*4 + (t>>6);
    tl[rr][t&63] = Vp[((size_t)h*N + k0 + rr)*64 + (t&63)];
  }
  __syncthreads();
  int w = k0>>10; int kw0 = k0 & 1023; int nw = N>>10;
  #pragma unroll
  for (int p=0;p<16;p++){
    int dd = p*4 + (t>>6);
    Vt[(((size_t)h*nw + w)*64 + dd)*1024 + kw0 + (t&63)] = tl[t&63][dd];
  }
}

// ---------------- windowed attention ----------------
#define ATTN_SCALE 0.14433756729740643f

__global__ __launch_bounds__(256) void attn_kernel(const u16* __restrict__ Qp, const u16* __restrict__ Kp,
    const u16* __restrict__ Vt, const int* __restrict__ order, u16* __restrict__ attn, int N, int nw)
{
  extern __shared__ char dsm[];
  float* S = (float*)dsm;                          // [16][1025] f32
  u16* P   = (u16*)(dsm + 16*1025*4);              // [16][1032] bf16
  u16* Ql  = (u16*)(dsm + 16*1025*4 + 16*1032*2);  // [16][64]
  float* Op = (float*)(dsm + 16*1025*4 + 16*1032*2 + 2048); // [4][16][48]
  int b = blockIdx.x;
  int qt = b & 63;
  int hw = b >> 6;
  int w = hw % nw, h = hw / nw;
  int t = threadIdx.x, lane=t&63, wv=t>>6;
  size_t base = ((size_t)h*N + (size_t)w*1024);
  if (t < 128){
    int row = t>>3, dc = (t&7)<<3;
    *(u16x8*)(Ql + row*64 + dc) = *(const u16x8*)(Qp + (base + qt*16 + row)*64 + dc);
  }
  __syncthreads();
  int fr = lane&15, fk = (lane>>4)<<3;
  s16x8 a0 = *(const s16x8*)(Ql + fr*64 + fk);
  s16x8 a1 = *(const s16x8*)(Ql + fr*64 + 32 + fk);
  for (int ct=wv; ct<64; ct+=4){
    const u16* kp = Kp + (base + ct*16 + fr)*64 + fk;
    s16x8 b0 = *(const s16x8*)kp;
    s16x8 b1 = *(const s16x8*)(kp + 32);
    fx4 acc = (fx4){0.f,0.f,0.f,0.f};
    acc = __builtin_amdgcn_mfma_f32_16x16x32_bf16(a0,b0,acc,0,0,0);
    acc = __builtin_amdgcn_mfma_f32_16x16x32_bf16(a1,b1,acc,0,0,0);
    int col = ct*16 + fr;
    int r0 = (lane>>4)<<2;
    #pragma unroll
    for (int j=0;j<4;j++) S[(r0+j)*1025 + col] = acc[j]*ATTN_SCALE;
  }
  __syncthreads();
  {
    int r = t>>4, c0 = t&15;
    float mxv = -3.4e38f;
    #pragma unroll 8
    for (int j=0;j<64;j++) mxv = fmaxf(mxv, S[r*1025 + c0 + 16*j]);
    #pragma unroll
    for (int m=1;m<16;m<<=1) mxv = fmaxf(mxv, __shfl_xor(mxv,m));
    float sum=0.f;
    #pragma unroll 8
    for (int j=0;j<64;j++){
      float e = expf(S[r*1025 + c0+16*j] - mxv);
      S[r*1025 + c0+16*j] = e;
      sum += e;
    }
    #pragma unroll
    for (int m=1;m<16;m<<=1) sum += __shfl_xor(sum,m);
    float inv = 1.0f/sum;
    #pragma unroll 8
    for (int j=0;j<64;j++) P[r*1032 + c0+16*j] = f2bf(S[r*1025 + c0+16*j]*inv);
  }
  __syncthreads();
  fx4 o0=(fx4){0.f,0.f,0.f,0.f}, o1=o0, o2=o0;
  size_t vbase = ((size_t)h*nw + w)*64;
  for (int s=0;s<8;s++){
    int kb0 = (wv*8+s)*32;
    s16x8 pa = *(const s16x8*)(P + fr*1032 + kb0 + fk);
    s16x8 v0 = *(const s16x8*)(Vt + (vbase + 0  + fr)*1024 + kb0 + fk);
    s16x8 v1 = *(const s16x8*)(Vt + (vbase + 16 + fr)*1024 + kb0 + fk);
    s16x8 v2 = *(const s16x8*)(Vt + (vbase + 32 + fr)*1024 + kb0 + fk);
    o0 = __builtin_amdgcn_mfma_f32_16x16x32_bf16(pa,v0,o0,0,0,0);
    o1 = __builtin_amdgcn_mfma_f32_16x16x32_bf16(pa,v1,o1,0,0,0);
    o2 = __builtin_amdgcn_mfma_f32_16x16x32_bf16(pa,v2,o2,0,0,0);
  }
  {
    int r0 = (lane>>4)<<2;
    #pragma unroll
    for (int j=0;j<4;j++){
      Op[(wv*16 + r0+j)*48 + 0  + fr] = o0[j];
      Op[(wv*16 + r0+j)*48 + 16 + fr] = o1[j];
      Op[(wv*16 + r0+j)*48 + 32 + fr] = o2[j];
    }
  }
  __syncthreads();
  for (int idx=t; idx<16*48; idx+=256){
    int rr = idx/48, dd = idx-rr*48;
    float v = Op[rr*48+dd] + Op[(16+rr)*48+dd] + Op[(32+rr)*48+dd] + Op[(48+rr)*48+dd];
    int orig = order[w*1024 + qt*16 + rr];
    attn[(size_t)orig*384 + h*48 + dd] = f2bf(v);
  }
}

// ---------------- LN2 (row-major input) ----------------
__global__ __launch_bounds__(256) void ln2_kernel(const float* __restrict__ y, const float* __restrict__ g,
    const float* __restrict__ b, u16* __restrict__ out, int N)
{
  int tok = (blockIdx.x<<2) + (threadIdx.x>>6);
  int lane = threadIdx.x & 63;
  const float* row = y + (size_t)tok*384;
  float v[6];
  #pragma unroll
  for (int j=0;j<6;j++) v[j] = row[lane + 64*j];
  float s = 0.f;
  #pragma unroll
  for (int j=0;j<6;j++) s += v[j];
  #pragma unroll
  for (int m=1;m<64;m<<=1) s += __shfl_xor(s,m);
  float mu = s*(1.0f/384.0f);
  float vr = 0.f;
  #pragma unroll
  for (int j=0;j<6;j++){ float d=v[j]-mu; vr += d*d; }
  #pragma unroll
  for (int m=1;m<64;m<<=1) vr += __shfl_xor(vr,m);
  float rs = rsqrtf(vr*(1.0f/384.0f) + 1e-5f);
  u16* dst = out + (size_t)tok*384;
  #pragma unroll
  for (int j=0;j<6;j++){
    int c = lane + 64*j;
    dst[c] = f2bf((v[j]-mu)*rs*g[c] + b[c]);
  }
}

extern "C" void kernel_launch(void* const* d_in, const int* in_sizes, int n_in,
                              void* d_out, int out_size, void* d_ws, size_t ws_size,
                              hipStream_t stream)
{
  (void)n_in; (void)out_size; (void)ws_size;
  const float* x     = (const float*)d_in[0];
  const float* xyz   = (const float*)d_in[1];
  const float* ln1_g = (const float*)d_in[2];
  const float* ln1_b = (const float*)d_in[3];
  const float* qkv_w = (const float*)d_in[4];
  const float* qkv_b = (const float*)d_in[5];
  const float* proj_w= (const float*)d_in[6];
  const float* proj_b= (const float*)d_in[7];
  const float* ln2_g = (const float*)d_in[8];
  const float* ln2_b = (const float*)d_in[9];
  const float* ffn_w1= (const float*)d_in[10];
  const float* ffn_b1= (const float*)d_in[11];
  const float* ffn_w2= (const float*)d_in[12];
  const float* ffn_b2= (const float*)d_in[13];
  int N = in_sizes[0]/384;
  int nw = N/1024;
  char* wsp = (char*)d_ws;
  size_t off = 0;
  auto alloc = [&](size_t bytes)->char*{ char* p = wsp + off; off = (off + bytes + 255) & ~(size_t)255; return p; };
  int*  order   = (int*)alloc((size_t)N*4);
  int*  gridS   = (int*)alloc((size_t)N*12);
  u16*  qkv_wT  = (u16*)alloc((size_t)1152*384*2);
  u16*  proj_wT = (u16*)alloc((size_t)384*384*2);
  u16*  w1T     = (u16*)alloc((size_t)1536*384*2);
  u16*  w2T     = (u16*)alloc((size_t)384*1536*2);
  u16*  xn      = (u16*)alloc((size_t)N*384*2);
  u16*  qkvb    = (u16*)alloc((size_t)N*1152*2);
  u16*  Qp      = (u16*)alloc((size_t)N*64*8*2);
  u16*  Kp      = (u16*)alloc((size_t)N*64*8*2);
  u16*  Vp      = (u16*)alloc((size_t)N*64*8*2);
  u16*  Vt      = (u16*)alloc((size_t)N*64*8*2);
  float* y1     = (float*)alloc((size_t)N*384*4);
  u16*  attn    = xn;     // xn dead after QKV gemm
  u16*  xn2     = qkvb;   // qkvb dead after rope_kernel
  u16*  mid     = Qp;     // Qp/Kp/Vp dead after attention; N*1536*2 == 3*(N*64*8*2)
  float* outF = (float*)d_out;

  sort_kernel<<<1, 1024, (size_t)N*8, stream>>>(xyz, order, gridS, N);
  wtrans_kernel<<<(1152/32)*(384/32), 256, 0, stream>>>(qkv_w, qkv_wT, 384, 1152);
  wtrans_kernel<<<(384/32)*(384/32), 256, 0, stream>>>(proj_w, proj_wT, 384, 384);
  wtrans_kernel<<<(1536/32)*(384/32), 256, 0, stream>>>(ffn_w1, w1T, 384, 1536);
  wtrans_kernel<<<(384/32)*(1536/32), 256, 0, stream>>>(ffn_w2, w2T, 1536, 384);
  ln1_kernel<<<N/64, 256, 64*388*4, stream>>>(x, ln1_g, ln1_b, xn, N);
  gemm_kernel<0><<<(N/64)*(1152/64), 256, 0, stream>>>(xn, qkv_wT, qkv_b, qkvb, nullptr, nullptr, N, 1152, 384);
  rope_kernel<<<N/64, 256, 0, stream>>>(qkvb, order, gridS, Qp, Kp, Vp, N);
  vtrans_kernel<<<8*(N/64), 256, 0, stream>>>(Vp, Vt, N);
  size_t attn_lds = 16*1025*4 + 16*1032*2 + 2048 + 4*16*48*4;
  attn_kernel<<<8*nw*64, 256, attn_lds, stream>>>(Qp, Kp, Vt, order, attn, N, nw);
  gemm_kernel<2><<<(N/64)*(384/64), 256, 0, stream>>>(attn, proj_wT, proj_b, nullptr, y1, x, N, 384, 384);
  ln2_kernel<<<N/4, 256, 0, stream>>>(y1, ln2_g, ln2_b, xn2, N);
  gemm_kernel<1><<<(N/64)*(1536/64), 256, 0, stream>>>(xn2, w1T, ffn_b1, mid, nullptr, nullptr, N, 1536, 384);
  gemm_kernel<3><<<(N/64)*(384/64), 256, 0, stream>>>(mid, w2T, ffn_b2, nullptr, outF, y1, N, 384, 1536);
}

// Round 2
// 826.113 us; speedup vs baseline: 2.3274x; 2.3274x over previous
//
#include <hip/hip_runtime.h>
#include <hip/hip_bf16.h>

typedef unsigned short u16;
typedef unsigned int u32;
typedef unsigned long long u64;
typedef __attribute__((ext_vector_type(8))) short s16x8;
typedef __attribute__((ext_vector_type(8))) unsigned short u16x8;
typedef __attribute__((ext_vector_type(4))) float fx4;
typedef __attribute__((ext_vector_type(4))) unsigned int ux4;

__device__ __forceinline__ float bf2f(u16 u){ u32 x=((u32)u)<<16; return __builtin_bit_cast(float,x); }
__device__ __forceinline__ u16 f2bf(float f){ u32 x=__builtin_bit_cast(u32,f); return (u16)((x + 0x7FFFu + ((x>>16)&1u))>>16); }

__device__ __forceinline__ u64 spread3(u32 v){
  u64 x = v & 0xFFFFull;
  x = (x | (x<<32)) & 0x001f00000000ffffull;
  x = (x | (x<<16)) & 0x001f0000ff0000ffull;
  x = (x | (x<<8))  & 0x100f00f00f00f00full;
  x = (x | (x<<4))  & 0x10c30c30c30c30c3ull;
  x = (x | (x<<2))  & 0x1249249249249249ull;
  return x;
}

// ---------------- sort stage 1: mins + keys + grid coords (original order) ----------------
__global__ __launch_bounds__(1024) void keys_init_kernel(const float* __restrict__ xyz,
        u64* __restrict__ keys, int* __restrict__ gridO, int N)
{
  __shared__ float red[3][16];
  __shared__ float mnS[3];
  int t = threadIdx.x; int lane = t&63; int wv = t>>6;
  float m0=3.4e38f,m1=3.4e38f,m2=3.4e38f;
  for (int i=t;i<N;i+=1024){
    m0=fminf(m0,xyz[i]); m1=fminf(m1,xyz[N+i]); m2=fminf(m2,xyz[2*N+i]);
  }
  for (int s=1;s<64;s<<=1){
    m0=fminf(m0,__shfl_xor(m0,s));
    m1=fminf(m1,__shfl_xor(m1,s));
    m2=fminf(m2,__shfl_xor(m2,s));
  }
  if (lane==0){ red[0][wv]=m0; red[1][wv]=m1; red[2][wv]=m2; }
  __syncthreads();
  if (t<3){ float m=red[t][0]; for(int i=1;i<16;i++) m=fminf(m,red[t][i]); mnS[t]=m; }
  __syncthreads();
  float mx0=mnS[0],mx1=mnS[1],mx2=mnS[2];
  for (int i=t;i<N;i+=1024){
    int gx=(int)((xyz[i]-mx0)/0.02f);     gx = gx<0?0:(gx>65535?65535:gx);
    int gy=(int)((xyz[N+i]-mx1)/0.02f);   gy = gy<0?0:(gy>65535?65535:gy);
    int gz=(int)((xyz[2*N+i]-mx2)/0.02f); gz = gz<0?0:(gz>65535?65535:gz);
    gridO[i*3+0]=gx; gridO[i*3+1]=gy; gridO[i*3+2]=gz;
    u64 mort = (spread3((u32)gx)<<2)|(spread3((u32)gy)<<1)|spread3((u32)gz);
    keys[i] = (mort<<14) | (u64)i;   // stable tie-break = ascending index
  }
}

// ---------------- sort stage 2: bitonic sort 2048-key runs in LDS ----------------
__global__ __launch_bounds__(1024) void bsort_kernel(u64* __restrict__ keys)
{
  __shared__ u64 sk[2048];
  int t = threadIdx.x;
  u64* base = keys + (size_t)blockIdx.x*2048;
  sk[t] = base[t]; sk[t+1024] = base[t+1024];
  for (int size=2; size<=2048; size<<=1){
    for (int stride=size>>1; stride>0; stride>>=1){
      __syncthreads();
      int i = 2*t - (t & (stride-1));
      int j = i + stride;
      u64 a = sk[i], b = sk[j];
      bool up = ((i & size) == 0);
      if ((a > b) == up){ sk[i]=b; sk[j]=a; }
    }
  }
  __syncthreads();
  base[t] = sk[t]; base[t+1024] = sk[t+1024];
}

// ---------------- sort stage 3: merge-path pairwise merge (runs of length L) ----------------
__global__ __launch_bounds__(256) void merge_kernel(const u64* __restrict__ src, u64* __restrict__ dst,
        int L, int N)
{
  int gt = blockIdx.x*256 + threadIdx.x;
  int d0 = gt*8;
  if (d0 >= N) return;
  int pair = d0 / (2*L);
  int base = pair*2*L;
  int ld = d0 - base;
  const u64* A = src + base;
  const u64* B = A + L;
  int lo = ld > L ? ld - L : 0;
  int hi = ld < L ? ld : L;
  while (lo < hi){
    int mid = (lo+hi)>>1;
    if (A[mid] <= B[ld-1-mid]) lo = mid+1; else hi = mid;
  }
  int i = lo, j = ld - lo;
  u64* out = dst + base + ld;
  u64 a = (i < L) ? A[i] : ~0ull;
  u64 b = (j < L) ? B[j] : ~0ull;
  #pragma unroll
  for (int e=0;e<8;e++){
    if (a <= b){ out[e] = a; i++; a = (i<L)?A[i]:~0ull; }
    else       { out[e] = b; j++; b = (j<L)?B[j]:~0ull; }
  }
}

// ---------------- sort stage 4: write order + gather grid coords to sorted order ----------------
__global__ __launch_bounds__(256) void finalize_kernel(const u64* __restrict__ keys, const int* __restrict__ gridO,
        int* __restrict__ order, int* __restrict__ gridS, int N)
{
  int i = blockIdx.x*256 + threadIdx.x;
  if (i >= N) return;
  int orig = (int)(keys[i] & 16383ull);
  order[i] = orig;
  gridS[i*3+0] = gridO[orig*3+0];
  gridS[i*3+1] = gridO[orig*3+1];
  gridS[i*3+2] = gridO[orig*3+2];
}

// ---------------- weight transpose -> bf16 (Nout, K) ----------------
__global__ __launch_bounds__(256) void wtrans_kernel(const float* __restrict__ W, u16* __restrict__ Wt, int K, int Nc)
{
  __shared__ float tl[32][33];
  int nb = Nc/32;
  int n0 = (blockIdx.x % nb)*32;
  int k0 = (blockIdx.x / nb)*32;
  int t=threadIdx.x; int r=t>>5, c=t&31;
  #pragma unroll
  for (int p=0;p<4;p++) tl[p*8+r][c] = W[(size_t)(k0+p*8+r)*Nc + n0+c];
  __syncthreads();
  #pragma unroll
  for (int p=0;p<4;p++) Wt[(size_t)(n0+p*8+r)*K + k0+c] = f2bf(tl[c][p*8+r]);
}

// ---------------- LN1 fused with (C,N)->(N,C) transpose ----------------
__global__ __launch_bounds__(256) void ln1_kernel(const float* __restrict__ x, const float* __restrict__ g,
     const float* __restrict__ b, u16* __restrict__ xn, int N)
{
  extern __shared__ char dsm[];
  float* tile = (float*)dsm; // [64][388]
  int n0 = blockIdx.x*64;
  int t = threadIdx.x;
  #pragma unroll 4
  for (int p=0;p<96;p++){
    int cc = p*4 + (t>>6);
    tile[(t&63)*388 + cc] = x[(size_t)cc*N + n0 + (t&63)];
  }
  __syncthreads();
  int tok = t>>2, part = t&3;
  const float* row = tile + tok*388 + part*96;
  float s=0.f;
  #pragma unroll
  for (int j=0;j<96;j++) s += row[j];
  s += __shfl_xor(s,1); s += __shfl_xor(s,2);
  float mu = s*(1.0f/384.0f);
  float vr=0.f;
  #pragma unroll
  for (int j=0;j<96;j++){ float d=row[j]-mu; vr += d*d; }
  vr += __shfl_xor(vr,1); vr += __shfl_xor(vr,2);
  float rs = rsqrtf(vr*(1.0f/384.0f) + 1e-5f);
  u16* dst = xn + (size_t)(n0+tok)*384 + part*96;
  #pragma unroll
  for (int q=0;q<12;q++){
    u16x8 o;
    #pragma unroll
    for (int j=0;j<8;j++){
      int c = part*96 + q*8 + j;
      o[j] = f2bf((row[q*8+j]-mu)*rs*g[c] + b[c]);
    }
    *(u16x8*)(dst + q*8) = o;
  }
}

// ---------------- generic bf16 MFMA GEMM with fused epilogues ----------------
__device__ __forceinline__ float gelu_f(float v){
  return 0.5f*v*(1.0f + erff(v*0.7071067811865475f));
}

// EPI 0: out bf16 = acc+bias          (QKV)
// EPI 1: out bf16 = gelu(acc+bias)    (FFN1)
// EPI 2: outF f32 = acc+bias+x^T      (proj, res = x (C,M))
// EPI 3: outF f32 (transposed store) = acc+bias+res (FFN2, res = y1 (M,Nout))
template<int EPI>
__global__ __launch_bounds__(256) void gemm_kernel(const u16* __restrict__ A, const u16* __restrict__ Bt,
    const float* __restrict__ bias, u16* __restrict__ outB, float* __restrict__ outF,
    const float* __restrict__ res, int M, int Nout, int K)
{
  __shared__ u16 Al[64][40];
  __shared__ u16 Bl[64][40];
  __shared__ float et[64][65];
  int nb = Nout>>6;
  int m0 = (blockIdx.x/nb)<<6;
  int n0 = (blockIdx.x%nb)<<6;
  int t = threadIdx.x, lane=t&63, wv=t>>6, wr=wv>>1, wc=wv&1;
  int lrow=t>>2, lcol=(t&3)<<3;
  fx4 acc[2][2];
  #pragma unroll
  for(int i=0;i<2;i++)
  #pragma unroll
  for(int j=0;j<2;j++) acc[i][j]=(fx4){0.f,0.f,0.f,0.f};
  const u16* Ap = A + (size_t)(m0+lrow)*K + lcol;
  const u16* Bp = Bt + (size_t)(n0+lrow)*K + lcol;
  int fr = lane&15, fk = (lane>>4)<<3;
  for (int k0=0;k0<K;k0+=32){
    *(ux4*)&Al[lrow][lcol] = *(const ux4*)(Ap+k0);
    *(ux4*)&Bl[lrow][lcol] = *(const ux4*)(Bp+k0);
    __syncthreads();
    s16x8 a0 = *(const s16x8*)&Al[wr*32+fr][fk];
    s16x8 a1 = *(const s16x8*)&Al[wr*32+16+fr][fk];
    s16x8 b0 = *(const s16x8*)&Bl[wc*32+fr][fk];
    s16x8 b1 = *(const s16x8*)&Bl[wc*32+16+fr][fk];
    acc[0][0] = __builtin_amdgcn_mfma_f32_16x16x32_bf16(a0,b0,acc[0][0],0,0,0);
    acc[0][1] = __builtin_amdgcn_mfma_f32_16x16x32_bf16(a0,b1,acc[0][1],0,0,0);
    acc[1][0] = __builtin_amdgcn_mfma_f32_16x16x32_bf16(a1,b0,acc[1][0],0,0,0);
    acc[1][1] = __builtin_amdgcn_mfma_f32_16x16x32_bf16(a1,b1,acc[1][1],0,0,0);
    __syncthreads();
  }
  int r0=(lane>>4)<<2;
  if (EPI==0 || EPI==1){
    #pragma unroll
    for (int mi=0;mi<2;mi++)
    #pragma unroll
    for (int ni=0;ni<2;ni++){
      int c = n0 + wc*32 + ni*16 + fr;
      float bi = bias[c];
      #pragma unroll
      for (int j=0;j<4;j++){
        int m = m0 + wr*32 + mi*16 + r0 + j;
        float vv = acc[mi][ni][j] + bi;
        if (EPI==1) vv = gelu_f(vv);
        outB[(size_t)m*Nout + c] = f2bf(vv);
      }
    }
  } else if (EPI==2){
    #pragma unroll
    for (int p=0;p<16;p++){
      int cc = p*4 + (t>>6);
      et[t&63][cc] = res[(size_t)(n0+cc)*M + m0 + (t&63)];
    }
    __syncthreads();
    #pragma unroll
    for (int mi=0;mi<2;mi++)
    #pragma unroll
    for (int ni=0;ni<2;ni++){
      int lc = wc*32 + ni*16 + fr;
      float bi = bias[n0+lc];
      #pragma unroll
      for (int j=0;j<4;j++){
        int lm = wr*32 + mi*16 + r0 + j;
        outF[(size_t)(m0+lm)*Nout + n0+lc] = acc[mi][ni][j] + bi + et[lm][lc];
      }
    }
  } else {
    #pragma unroll
    for (int mi=0;mi<2;mi++)
    #pragma unroll
    for (int ni=0;ni<2;ni++){
      int lc = wc*32 + ni*16 + fr;
      float bi = bias[n0+lc];
      #pragma unroll
      for (int j=0;j<4;j++){
        int lm = wr*32 + mi*16 + r0 + j;
        et[lm][lc] = acc[mi][ni][j] + bi + res[(size_t)(m0+lm)*Nout + n0+lc];
      }
    }
    __syncthreads();
    #pragma unroll
    for (int p=0;p<16;p++){
      int cc = p*4 + (t>>6);
      outF[(size_t)(n0+cc)*M + m0 + (t&63)] = et[t&63][cc];
    }
  }
}

// ---------------- RoPE + gather-into-sorted-window layout ----------------
__global__ __launch_bounds__(256) void rope_kernel(const u16* __restrict__ qkv, const int* __restrict__ order,
    const int* __restrict__ gridS, u16* __restrict__ Qp, u16* __restrict__ Kp, u16* __restrict__ Vp, int N)
{
  __shared__ float csm[64][24][2];
  __shared__ int origs[64];
  int i0 = blockIdx.x<<6;
  int t = threadIdx.x;
  if (t<64) origs[t] = order[i0+t];
  for (int idx=t; idx<64*24; idx+=256){
    int tok = idx/24, slot = idx - tok*24;
    int a = slot>>3, fi = slot&7;
    int pos = gridS[(size_t)(i0+tok)*3 + a];
    pos = pos<0?0:(pos>4095?4095:pos);
    float invf = powf(100.0f, -(float)fi*0.125f);
    float ang = (float)pos * invf;
    csm[tok][slot][0] = cosf(ang);
    csm[tok][slot][1] = sinf(ang);
  }
  __syncthreads();
  int tok = t&63;
  int i = i0 + tok;
  const u16* src = qkv + (size_t)origs[tok]*1152;
  u16x8 zz = {0,0,0,0,0,0,0,0};
  for (int h=t>>6; h<8; h+=4){
    size_t dst = ((size_t)h*N + i)*64;
    #pragma unroll
    for (int a=0;a<3;a++){
      u16x8 qa = *(const u16x8*)(src + h*48 + a*16);
      u16x8 qb = *(const u16x8*)(src + h*48 + a*16 + 8);
      u16x8 ka = *(const u16x8*)(src + 384 + h*48 + a*16);
      u16x8 kb = *(const u16x8*)(src + 384 + h*48 + a*16 + 8);
      u16x8 oqa, oqb, oka, okb;
      #pragma unroll
      for (int j=0;j<8;j++){
        float c0 = csm[tok][a*8+j][0], s0 = csm[tok][a*8+j][1];
        float ql = bf2f(qa[j]), qh = bf2f(qb[j]);
        float kl = bf2f(ka[j]), kh = bf2f(kb[j]);
        oqa[j] = f2bf(ql*c0 - qh*s0);
        oqb[j] = f2bf(qh*c0 + ql*s0);
        oka[j] = f2bf(kl*c0 - kh*s0);
        okb[j] = f2bf(kh*c0 + kl*s0);
      }
      *(u16x8*)(Qp + dst + a*16) = oqa;
      *(u16x8*)(Qp + dst + a*16 + 8) = oqb;
      *(u16x8*)(Kp + dst + a*16) = oka;
      *(u16x8*)(Kp + dst + a*16 + 8) = okb;
      u16x8 va = *(const u16x8*)(src + 768 + h*48 + a*16);
      u16x8 vb = *(const u16x8*)(src + 768 + h*48 + a*16 + 8);
      *(u16x8*)(Vp + dst + a*16) = va;
      *(u16x8*)(Vp + dst + a*16 + 8) = vb;
    }
    *(u16x8*)(Qp + dst + 48) = zz; *(u16x8*)(Qp + dst + 56) = zz;
    *(u16x8*)(Kp + dst + 48) = zz; *(u16x8*)(Kp + dst + 56) = zz;
    *(u16x8*)(Vp + dst + 48) = zz; *(u16x8*)(Vp + dst + 56) = zz;
  }
}

// ---------------- V transpose to (h, w, d64, k1024) ----------------
__global__ __launch_bounds__(256) void vtrans_kernel(const u16* __restrict__ Vp, u16* __restrict__ Vt, int N)
{
  __shared__ u16 tl[64][65];
  int nkb = N>>6;
  int h = blockIdx.x / nkb;
  int k0 = (blockIdx.x % nkb)<<6;
  int t=threadIdx.x;
  #pragma unroll
  for (int p=0;p<16;p++){
    int rr = p*4 + (t>>6);
    tl[rr][t&63] = Vp[((size_t)h*N + k0 + rr)*64 + (t&63)];
  }
  __syncthreads();
  int w = k0>>10; int kw0 = k0 & 1023; int nw = N>>10;
  #pragma unroll
  for (int p=0;p<16;p++){
    int dd = p*4 + (t>>6);
    Vt[(((size_t)h*nw + w)*64 + dd)*1024 + kw0 + (t&63)] = tl[t&63][dd];
  }
}

// ---------------- windowed attention ----------------
#define ATTN_SCALE 0.14433756729740643f

__global__ __launch_bounds__(256) void attn_kernel(const u16* __restrict__ Qp, const u16* __restrict__ Kp,
    const u16* __restrict__ Vt, const int* __restrict__ order, u16* __restrict__ attn, int N, int nw)
{
  extern __shared__ char dsm[];
  float* S = (float*)dsm;                          // [16][1025] f32
  u16* P   = (u16*)(dsm + 16*1025*4);              // [16][1032] bf16
  u16* Ql  = (u16*)(dsm + 16*1025*4 + 16*1032*2);  // [16][64]
  float* Op = (float*)(dsm + 16*1025*4 + 16*1032*2 + 2048); // [4][16][48]
  int b = blockIdx.x;
  int qt = b & 63;
  int hw = b >> 6;
  int w = hw % nw, h = hw / nw;
  int t = threadIdx.x, lane=t&63, wv=t>>6;
  size_t base = ((size_t)h*N + (size_t)w*1024);
  if (t < 128){
    int row = t>>3, dc = (t&7)<<3;
    *(u16x8*)(Ql + row*64 + dc) = *(const u16x8*)(Qp + (base + qt*16 + row)*64 + dc);
  }
  __syncthreads();
  int fr = lane&15, fk = (lane>>4)<<3;
  s16x8 a0 = *(const s16x8*)(Ql + fr*64 + fk);
  s16x8 a1 = *(const s16x8*)(Ql + fr*64 + 32 + fk);
  for (int ct=wv; ct<64; ct+=4){
    const u16* kp = Kp + (base + ct*16 + fr)*64 + fk;
    s16x8 b0 = *(const s16x8*)kp;
    s16x8 b1 = *(const s16x8*)(kp + 32);
    fx4 acc = (fx4){0.f,0.f,0.f,0.f};
    acc = __builtin_amdgcn_mfma_f32_16x16x32_bf16(a0,b0,acc,0,0,0);
    acc = __builtin_amdgcn_mfma_f32_16x16x32_bf16(a1,b1,acc,0,0,0);
    int col = ct*16 + fr;
    int r0 = (lane>>4)<<2;
    #pragma unroll
    for (int j=0;j<4;j++) S[(r0+j)*1025 + col] = acc[j]*ATTN_SCALE;
  }
  __syncthreads();
  {
    int r = t>>4, c0 = t&15;
    float mxv = -3.4e38f;
    #pragma unroll 8
    for (int j=0;j<64;j++) mxv = fmaxf(mxv, S[r*1025 + c0 + 16*j]);
    #pragma unroll
    for (int m=1;m<16;m<<=1) mxv = fmaxf(mxv, __shfl_xor(mxv,m));
    float sum=0.f;
    #pragma unroll 8
    for (int j=0;j<64;j++){
      float e = expf(S[r*1025 + c0+16*j] - mxv);
      S[r*1025 + c0+16*j] = e;
      sum += e;
    }
    #pragma unroll
    for (int m=1;m<16;m<<=1) sum += __shfl_xor(sum,m);
    float inv = 1.0f/sum;
    #pragma unroll 8
    for (int j=0;j<64;j++) P[r*1032 + c0+16*j] = f2bf(S[r*1025 + c0+16*j]*inv);
  }
  __syncthreads();
  fx4 o0=(fx4){0.f,0.f,0.f,0.f}, o1=o0, o2=o0;
  size_t vbase = ((size_t)h*nw + w)*64;
  for (int s=0;s<8;s++){
    int kb0 = (wv*8+s)*32;
    s16x8 pa = *(const s16x8*)(P + fr*1032 + kb0 + fk);
    s16x8 v0 = *(const s16x8*)(Vt + (vbase + 0  + fr)*1024 + kb0 + fk);
    s16x8 v1 = *(const s16x8*)(Vt + (vbase + 16 + fr)*1024 + kb0 + fk);
    s16x8 v2 = *(const s16x8*)(Vt + (vbase + 32 + fr)*1024 + kb0 + fk);
    o0 = __builtin_amdgcn_mfma_f32_16x16x32_bf16(pa,v0,o0,0,0,0);
    o1 = __builtin_amdgcn_mfma_f32_16x16x32_bf16(pa,v1,o1,0,0,0);
    o2 = __builtin_amdgcn_mfma_f32_16x16x32_bf16(pa,v2,o2,0,0,0);
  }
  {
    int r0 = (lane>>4)<<2;
    #pragma unroll
    for (int j=0;j<4;j++){
      Op[(wv*16 + r0+j)*48 + 0  + fr] = o0[j];
      Op[(wv*16 + r0+j)*48 + 16 + fr] = o1[j];
      Op[(wv*16 + r0+j)*48 + 32 + fr] = o2[j];
    }
  }
  __syncthreads();
  for (int idx=t; idx<16*48; idx+=256){
    int rr = idx/48, dd = idx-rr*48;
    float v = Op[rr*48+dd] + Op[(16+rr)*48+dd] + Op[(32+rr)*48+dd] + Op[(48+rr)*48+dd];
    int orig = order[w*1024 + qt*16 + rr];
    attn[(size_t)orig*384 + h*48 + dd] = f2bf(v);
  }
}

// ---------------- LN2 (row-major input) ----------------
__global__ __launch_bounds__(256) void ln2_kernel(const float* __restrict__ y, const float* __restrict__ g,
    const float* __restrict__ b, u16* __restrict__ out, int N)
{
  int tok = (blockIdx.x<<2) + (threadIdx.x>>6);
  int lane = threadIdx.x & 63;
  const float* row = y + (size_t)tok*384;
  float v[6];
  #pragma unroll
  for (int j=0;j<6;j++) v[j] = row[lane + 64*j];
  float s = 0.f;
  #pragma unroll
  for (int j=0;j<6;j++) s += v[j];
  #pragma unroll
  for (int m=1;m<64;m<<=1) s += __shfl_xor(s,m);
  float mu = s*(1.0f/384.0f);
  float vr = 0.f;
  #pragma unroll
  for (int j=0;j<6;j++){ float d=v[j]-mu; vr += d*d; }
  #pragma unroll
  for (int m=1;m<64;m<<=1) vr += __shfl_xor(vr,m);
  float rs = rsqrtf(vr*(1.0f/384.0f) + 1e-5f);
  u16* dst = out + (size_t)tok*384;
  #pragma unroll
  for (int j=0;j<6;j++){
    int c = lane + 64*j;
    dst[c] = f2bf((v[j]-mu)*rs*g[c] + b[c]);
  }
}

extern "C" void kernel_launch(void* const* d_in, const int* in_sizes, int n_in,
                              void* d_out, int out_size, void* d_ws, size_t ws_size,
                              hipStream_t stream)
{
  (void)n_in; (void)out_size; (void)ws_size;
  const float* x     = (const float*)d_in[0];
  const float* xyz   = (const float*)d_in[1];
  const float* ln1_g = (const float*)d_in[2];
  const float* ln1_b = (const float*)d_in[3];
  const float* qkv_w = (const float*)d_in[4];
  const float* qkv_b = (const float*)d_in[5];
  const float* proj_w= (const float*)d_in[6];
  const float* proj_b= (const float*)d_in[7];
  const float* ln2_g = (const float*)d_in[8];
  const float* ln2_b = (const float*)d_in[9];
  const float* ffn_w1= (const float*)d_in[10];
  const float* ffn_b1= (const float*)d_in[11];
  const float* ffn_w2= (const float*)d_in[12];
  const float* ffn_b2= (const float*)d_in[13];
  int N = in_sizes[0]/384;
  int nw = N/1024;
  char* wsp = (char*)d_ws;
  size_t off = 0;
  auto alloc = [&](size_t bytes)->char*{ char* p = wsp + off; off = (off + bytes + 255) & ~(size_t)255; return p; };
  int*  order   = (int*)alloc((size_t)N*4);
  int*  gridS   = (int*)alloc((size_t)N*12);
  int*  gridO   = (int*)alloc((size_t)N*12);
  u64*  keysA   = (u64*)alloc((size_t)N*8);
  u64*  keysB   = (u64*)alloc((size_t)N*8);
  u16*  qkv_wT  = (u16*)alloc((size_t)1152*384*2);
  u16*  proj_wT = (u16*)alloc((size_t)384*384*2);
  u16*  w1T     = (u16*)alloc((size_t)1536*384*2);
  u16*  w2T     = (u16*)alloc((size_t)384*1536*2);
  u16*  xn      = (u16*)alloc((size_t)N*384*2);
  u16*  qkvb    = (u16*)alloc((size_t)N*1152*2);
  u16*  Qp      = (u16*)alloc((size_t)N*64*8*2);
  u16*  Kp      = (u16*)alloc((size_t)N*64*8*2);
  u16*  Vp      = (u16*)alloc((size_t)N*64*8*2);
  u16*  Vt      = (u16*)alloc((size_t)N*64*8*2);
  float* y1     = (float*)alloc((size_t)N*384*4);
  u16*  attn    = xn;     // xn dead after QKV gemm
  u16*  xn2     = qkvb;   // qkvb dead after rope_kernel
  u16*  mid     = Qp;     // Qp/Kp/Vp dead after attention; N*1536*2 == 3*(N*64*8*2)
  float* outF = (float*)d_out;

  // ---- parallel Z-order sort: keys -> 2048-run bitonic -> 3 merge rounds -> finalize ----
  keys_init_kernel<<<1, 1024, 0, stream>>>(xyz, keysA, gridO, N);
  bsort_kernel<<<N/2048, 1024, 0, stream>>>(keysA);
  merge_kernel<<<N/2048, 256, 0, stream>>>(keysA, keysB, 2048, N);
  merge_kernel<<<N/2048, 256, 0, stream>>>(keysB, keysA, 4096, N);
  merge_kernel<<<N/2048, 256, 0, stream>>>(keysA, keysB, 8192, N);
  finalize_kernel<<<N/256, 256, 0, stream>>>(keysB, gridO, order, gridS, N);

  wtrans_kernel<<<(1152/32)*(384/32), 256, 0, stream>>>(qkv_w, qkv_wT, 384, 1152);
  wtrans_kernel<<<(384/32)*(384/32), 256, 0, stream>>>(proj_w, proj_wT, 384, 384);
  wtrans_kernel<<<(1536/32)*(384/32), 256, 0, stream>>>(ffn_w1, w1T, 384, 1536);
  wtrans_kernel<<<(384/32)*(1536/32), 256, 0, stream>>>(ffn_w2, w2T, 1536, 384);
  ln1_kernel<<<N/64, 256, 64*388*4, stream>>>(x, ln1_g, ln1_b, xn, N);
  gemm_kernel<0><<<(N/64)*(1152/64), 256, 0, stream>>>(xn, qkv_wT, qkv_b, qkvb, nullptr, nullptr, N, 1152, 384);
  rope_kernel<<<N/64, 256, 0, stream>>>(qkvb, order, gridS, Qp, Kp, Vp, N);
  vtrans_kernel<<<8*(N/64), 256, 0, stream>>>(Vp, Vt, N);
  size_t attn_lds = 16*1025*4 + 16*1032*2 + 2048 + 4*16*48*4;
  attn_kernel<<<8*nw*64, 256, attn_lds, stream>>>(Qp, Kp, Vt, order, attn, N, nw);
  gemm_kernel<2><<<(N/64)*(384/64), 256, 0, stream>>>(attn, proj_wT, proj_b, nullptr, y1, x, N, 384, 384);
  ln2_kernel<<<N/4, 256, 0, stream>>>(y1, ln2_g, ln2_b, xn2, N);
  gemm_kernel<1><<<(N/64)*(1536/64), 256, 0, stream>>>(xn2, w1T, ffn_b1, mid, nullptr, nullptr, N, 1536, 384);
  gemm_kernel<3><<<(N/64)*(384/64), 256, 0, stream>>>(mid, w2T, ffn_b2, nullptr, outF, y1, N, 384, 1536);
}

// Round 3
// 369.227 us; speedup vs baseline: 5.2074x; 2.2374x over previous
//
#include <hip/hip_runtime.h>
#include <hip/hip_bf16.h>

typedef unsigned short u16;
typedef unsigned int u32;
typedef unsigned long long u64;
typedef __attribute__((ext_vector_type(8))) short s16x8;
typedef __attribute__((ext_vector_type(4))) short s16x4;
typedef __attribute__((ext_vector_type(8))) unsigned short u16x8;
typedef __attribute__((ext_vector_type(4))) unsigned short u16x4;
typedef __attribute__((ext_vector_type(4))) float fx4;
typedef __attribute__((ext_vector_type(4))) unsigned int ux4;

__device__ __forceinline__ float bf2f(u16 u){ u32 x=((u32)u)<<16; return __builtin_bit_cast(float,x); }
__device__ __forceinline__ u16 f2bf(float f){ u32 x=__builtin_bit_cast(u32,f); return (u16)((x + 0x7FFFu + ((x>>16)&1u))>>16); }

__device__ __forceinline__ s16x8 ld_bf8(const u16* p){
  s16x4 lo = *(const s16x4*)p;
  s16x4 hi = *(const s16x4*)(p+4);
  s16x8 r;
  r[0]=lo[0]; r[1]=lo[1]; r[2]=lo[2]; r[3]=lo[3];
  r[4]=hi[0]; r[5]=hi[1]; r[6]=hi[2]; r[7]=hi[3];
  return r;
}

__device__ __forceinline__ u64 spread3(u32 v){
  u64 x = v & 0xFFFFull;
  x = (x | (x<<32)) & 0x001f00000000ffffull;
  x = (x | (x<<16)) & 0x001f0000ff0000ffull;
  x = (x | (x<<8))  & 0x100f00f00f00f00full;
  x = (x | (x<<4))  & 0x10c30c30c30c30c3ull;
  x = (x | (x<<2))  & 0x1249249249249249ull;
  return x;
}

// ---------------- sort stage 1: mins + keys + grid coords (original order) ----------------
__global__ __launch_bounds__(1024) void keys_init_kernel(const float* __restrict__ xyz,
        u64* __restrict__ keys, int* __restrict__ gridO, int N)
{
  __shared__ float red[3][16];
  __shared__ float mnS[3];
  int t = threadIdx.x; int lane = t&63; int wv = t>>6;
  float m0=3.4e38f,m1=3.4e38f,m2=3.4e38f;
  for (int i=t;i<N;i+=1024){
    m0=fminf(m0,xyz[i]); m1=fminf(m1,xyz[N+i]); m2=fminf(m2,xyz[2*N+i]);
  }
  for (int s=1;s<64;s<<=1){
    m0=fminf(m0,__shfl_xor(m0,s));
    m1=fminf(m1,__shfl_xor(m1,s));
    m2=fminf(m2,__shfl_xor(m2,s));
  }
  if (lane==0){ red[0][wv]=m0; red[1][wv]=m1; red[2][wv]=m2; }
  __syncthreads();
  if (t<3){ float m=red[t][0]; for(int i=1;i<16;i++) m=fminf(m,red[t][i]); mnS[t]=m; }
  __syncthreads();
  float mx0=mnS[0],mx1=mnS[1],mx2=mnS[2];
  for (int i=t;i<N;i+=1024){
    int gx=(int)((xyz[i]-mx0)/0.02f);     gx = gx<0?0:(gx>65535?65535:gx);
    int gy=(int)((xyz[N+i]-mx1)/0.02f);   gy = gy<0?0:(gy>65535?65535:gy);
    int gz=(int)((xyz[2*N+i]-mx2)/0.02f); gz = gz<0?0:(gz>65535?65535:gz);
    gridO[i*3+0]=gx; gridO[i*3+1]=gy; gridO[i*3+2]=gz;
    u64 mort = (spread3((u32)gx)<<2)|(spread3((u32)gy)<<1)|spread3((u32)gz);
    keys[i] = (mort<<14) | (u64)i;   // stable tie-break = ascending index
  }
}

// ---------------- sort stage 2: bitonic sort 2048-key runs in LDS ----------------
__global__ __launch_bounds__(1024) void bsort_kernel(u64* __restrict__ keys)
{
  __shared__ u64 sk[2048];
  int t = threadIdx.x;
  u64* base = keys + (size_t)blockIdx.x*2048;
  sk[t] = base[t]; sk[t+1024] = base[t+1024];
  for (int size=2; size<=2048; size<<=1){
    for (int stride=size>>1; stride>0; stride>>=1){
      __syncthreads();
      int i = 2*t - (t & (stride-1));
      int j = i + stride;
      u64 a = sk[i], b = sk[j];
      bool up = ((i & size) == 0);
      if ((a > b) == up){ sk[i]=b; sk[j]=a; }
    }
  }
  __syncthreads();
  base[t] = sk[t]; base[t+1024] = sk[t+1024];
}

// ---------------- sort stage 3: merge-path pairwise merge (runs of length L) ----------------
__global__ __launch_bounds__(256) void merge_kernel(const u64* __restrict__ src, u64* __restrict__ dst,
        int L, int N)
{
  int gt = blockIdx.x*256 + threadIdx.x;
  int d0 = gt*8;
  if (d0 >= N) return;
  int pair = d0 / (2*L);
  int base = pair*2*L;
  int ld = d0 - base;
  const u64* A = src + base;
  const u64* B = A + L;
  int lo = ld > L ? ld - L : 0;
  int hi = ld < L ? ld : L;
  while (lo < hi){
    int mid = (lo+hi)>>1;
    if (A[mid] <= B[ld-1-mid]) lo = mid+1; else hi = mid;
  }
  int i = lo, j = ld - lo;
  u64* out = dst + base + ld;
  u64 a = (i < L) ? A[i] : ~0ull;
  u64 b = (j < L) ? B[j] : ~0ull;
  #pragma unroll
  for (int e=0;e<8;e++){
    if (a <= b){ out[e] = a; i++; a = (i<L)?A[i]:~0ull; }
    else       { out[e] = b; j++; b = (j<L)?B[j]:~0ull; }
  }
}

// ---------------- sort stage 4: write order + gather grid coords to sorted order ----------------
__global__ __launch_bounds__(256) void finalize_kernel(const u64* __restrict__ keys, const int* __restrict__ gridO,
        int* __restrict__ order, int* __restrict__ gridS, int N)
{
  int i = blockIdx.x*256 + threadIdx.x;
  if (i >= N) return;
  int orig = (int)(keys[i] & 16383ull);
  order[i] = orig;
  gridS[i*3+0] = gridO[orig*3+0];
  gridS[i*3+1] = gridO[orig*3+1];
  gridS[i*3+2] = gridO[orig*3+2];
}

// ---------------- weight transpose -> bf16 (Nout, K) ----------------
__global__ __launch_bounds__(256) void wtrans_kernel(const float* __restrict__ W, u16* __restrict__ Wt, int K, int Nc)
{
  __shared__ float tl[32][33];
  int nb = Nc/32;
  int n0 = (blockIdx.x % nb)*32;
  int k0 = (blockIdx.x / nb)*32;
  int t=threadIdx.x; int r=t>>5, c=t&31;
  #pragma unroll
  for (int p=0;p<4;p++) tl[p*8+r][c] = W[(size_t)(k0+p*8+r)*Nc + n0+c];
  __syncthreads();
  #pragma unroll
  for (int p=0;p<4;p++) Wt[(size_t)(n0+p*8+r)*K + k0+c] = f2bf(tl[c][p*8+r]);
}

// ---------------- LN1 fused with (C,N)->(N,C) transpose ----------------
__global__ __launch_bounds__(256) void ln1_kernel(const float* __restrict__ x, const float* __restrict__ g,
     const float* __restrict__ b, u16* __restrict__ xn, int N)
{
  extern __shared__ char dsm[];
  float* tile = (float*)dsm; // [64][388]
  int n0 = blockIdx.x*64;
  int t = threadIdx.x;
  #pragma unroll 4
  for (int p=0;p<96;p++){
    int cc = p*4 + (t>>6);
    tile[(t&63)*388 + cc] = x[(size_t)cc*N + n0 + (t&63)];
  }
  __syncthreads();
  int tok = t>>2, part = t&3;
  const float* row = tile + tok*388 + part*96;
  float s=0.f;
  #pragma unroll
  for (int j=0;j<96;j++) s += row[j];
  s += __shfl_xor(s,1); s += __shfl_xor(s,2);
  float mu = s*(1.0f/384.0f);
  float vr=0.f;
  #pragma unroll
  for (int j=0;j<96;j++){ float d=row[j]-mu; vr += d*d; }
  vr += __shfl_xor(vr,1); vr += __shfl_xor(vr,2);
  float rs = rsqrtf(vr*(1.0f/384.0f) + 1e-5f);
  u16* dst = xn + (size_t)(n0+tok)*384 + part*96;
  #pragma unroll
  for (int q=0;q<12;q++){
    u16x8 o;
    #pragma unroll
    for (int j=0;j<8;j++){
      int c = part*96 + q*8 + j;
      o[j] = f2bf((row[q*8+j]-mu)*rs*g[c] + b[c]);
    }
    *(u16x8*)(dst + q*8) = o;
  }
}

// ---------------- generic bf16 MFMA GEMM with fused epilogues ----------------
__device__ __forceinline__ float gelu_f(float v){
  return 0.5f*v*(1.0f + erff(v*0.7071067811865475f));
}

// EPI 0: out bf16 = acc+bias          (QKV)
// EPI 1: out bf16 = gelu(acc+bias)    (FFN1)
// EPI 2: outF f32 = acc+bias+x^T      (proj, res = x (C,M))
// EPI 3: outF f32 (transposed store) = acc+bias+res (FFN2, res = y1 (M,Nout))
template<int EPI>
__global__ __launch_bounds__(256) void gemm_kernel(const u16* __restrict__ A, const u16* __restrict__ Bt,
    const float* __restrict__ bias, u16* __restrict__ outB, float* __restrict__ outF,
    const float* __restrict__ res, int M, int Nout, int K)
{
  __shared__ u16 Al[64][40];
  __shared__ u16 Bl[64][40];
  __shared__ float et[64][65];
  int nb = Nout>>6;
  int m0 = (blockIdx.x/nb)<<6;
  int n0 = (blockIdx.x%nb)<<6;
  int t = threadIdx.x, lane=t&63, wv=t>>6, wr=wv>>1, wc=wv&1;
  int lrow=t>>2, lcol=(t&3)<<3;
  fx4 acc[2][2];
  #pragma unroll
  for(int i=0;i<2;i++)
  #pragma unroll
  for(int j=0;j<2;j++) acc[i][j]=(fx4){0.f,0.f,0.f,0.f};
  const u16* Ap = A + (size_t)(m0+lrow)*K + lcol;
  const u16* Bp = Bt + (size_t)(n0+lrow)*K + lcol;
  int fr = lane&15, fk = (lane>>4)<<3;
  for (int k0=0;k0<K;k0+=32){
    *(ux4*)&Al[lrow][lcol] = *(const ux4*)(Ap+k0);
    *(ux4*)&Bl[lrow][lcol] = *(const ux4*)(Bp+k0);
    __syncthreads();
    s16x8 a0 = *(const s16x8*)&Al[wr*32+fr][fk];
    s16x8 a1 = *(const s16x8*)&Al[wr*32+16+fr][fk];
    s16x8 b0 = *(const s16x8*)&Bl[wc*32+fr][fk];
    s16x8 b1 = *(const s16x8*)&Bl[wc*32+16+fr][fk];
    acc[0][0] = __builtin_amdgcn_mfma_f32_16x16x32_bf16(a0,b0,acc[0][0],0,0,0);
    acc[0][1] = __builtin_amdgcn_mfma_f32_16x16x32_bf16(a0,b1,acc[0][1],0,0,0);
    acc[1][0] = __builtin_amdgcn_mfma_f32_16x16x32_bf16(a1,b0,acc[1][0],0,0,0);
    acc[1][1] = __builtin_amdgcn_mfma_f32_16x16x32_bf16(a1,b1,acc[1][1],0,0,0);
    __syncthreads();
  }
  int r0=(lane>>4)<<2;
  if (EPI==0 || EPI==1){
    #pragma unroll
    for (int mi=0;mi<2;mi++)
    #pragma unroll
    for (int ni=0;ni<2;ni++){
      int c = n0 + wc*32 + ni*16 + fr;
      float bi = bias[c];
      #pragma unroll
      for (int j=0;j<4;j++){
        int m = m0 + wr*32 + mi*16 + r0 + j;
        float vv = acc[mi][ni][j] + bi;
        if (EPI==1) vv = gelu_f(vv);
        outB[(size_t)m*Nout + c] = f2bf(vv);
      }
    }
  } else if (EPI==2){
    #pragma unroll
    for (int p=0;p<16;p++){
      int cc = p*4 + (t>>6);
      et[t&63][cc] = res[(size_t)(n0+cc)*M + m0 + (t&63)];
    }
    __syncthreads();
    #pragma unroll
    for (int mi=0;mi<2;mi++)
    #pragma unroll
    for (int ni=0;ni<2;ni++){
      int lc = wc*32 + ni*16 + fr;
      float bi = bias[n0+lc];
      #pragma unroll
      for (int j=0;j<4;j++){
        int lm = wr*32 + mi*16 + r0 + j;
        outF[(size_t)(m0+lm)*Nout + n0+lc] = acc[mi][ni][j] + bi + et[lm][lc];
      }
    }
  } else {
    #pragma unroll
    for (int mi=0;mi<2;mi++)
    #pragma unroll
    for (int ni=0;ni<2;ni++){
      int lc = wc*32 + ni*16 + fr;
      float bi = bias[n0+lc];
      #pragma unroll
      for (int j=0;j<4;j++){
        int lm = wr*32 + mi*16 + r0 + j;
        et[lm][lc] = acc[mi][ni][j] + bi + res[(size_t)(m0+lm)*Nout + n0+lc];
      }
    }
    __syncthreads();
    #pragma unroll
    for (int p=0;p<16;p++){
      int cc = p*4 + (t>>6);
      outF[(size_t)(n0+cc)*M + m0 + (t&63)] = et[t&63][cc];
    }
  }
}

// ---------------- RoPE + gather-into-sorted-window layout ----------------
__global__ __launch_bounds__(256) void rope_kernel(const u16* __restrict__ qkv, const int* __restrict__ order,
    const int* __restrict__ gridS, u16* __restrict__ Qp, u16* __restrict__ Kp, u16* __restrict__ Vp, int N)
{
  __shared__ float csm[64][24][2];
  __shared__ int origs[64];
  int i0 = blockIdx.x<<6;
  int t = threadIdx.x;
  if (t<64) origs[t] = order[i0+t];
  for (int idx=t; idx<64*24; idx+=256){
    int tok = idx/24, slot = idx - tok*24;
    int a = slot>>3, fi = slot&7;
    int pos = gridS[(size_t)(i0+tok)*3 + a];
    pos = pos<0?0:(pos>4095?4095:pos);
    float invf = powf(100.0f, -(float)fi*0.125f);
    float ang = (float)pos * invf;
    csm[tok][slot][0] = cosf(ang);
    csm[tok][slot][1] = sinf(ang);
  }
  __syncthreads();
  int tok = t&63;
  int i = i0 + tok;
  const u16* src = qkv + (size_t)origs[tok]*1152;
  u16x8 zz = {0,0,0,0,0,0,0,0};
  for (int h=t>>6; h<8; h+=4){
    size_t dst = ((size_t)h*N + i)*64;
    #pragma unroll
    for (int a=0;a<3;a++){
      u16x8 qa = *(const u16x8*)(src + h*48 + a*16);
      u16x8 qb = *(const u16x8*)(src + h*48 + a*16 + 8);
      u16x8 ka = *(const u16x8*)(src + 384 + h*48 + a*16);
      u16x8 kb = *(const u16x8*)(src + 384 + h*48 + a*16 + 8);
      u16x8 oqa, oqb, oka, okb;
      #pragma unroll
      for (int j=0;j<8;j++){
        float c0 = csm[tok][a*8+j][0], s0 = csm[tok][a*8+j][1];
        float ql = bf2f(qa[j]), qh = bf2f(qb[j]);
        float kl = bf2f(ka[j]), kh = bf2f(kb[j]);
        oqa[j] = f2bf(ql*c0 - qh*s0);
        oqb[j] = f2bf(qh*c0 + ql*s0);
        oka[j] = f2bf(kl*c0 - kh*s0);
        okb[j] = f2bf(kh*c0 + kl*s0);
      }
      *(u16x8*)(Qp + dst + a*16) = oqa;
      *(u16x8*)(Qp + dst + a*16 + 8) = oqb;
      *(u16x8*)(Kp + dst + a*16) = oka;
      *(u16x8*)(Kp + dst + a*16 + 8) = okb;
      u16x8 va = *(const u16x8*)(src + 768 + h*48 + a*16);
      u16x8 vb = *(const u16x8*)(src + 768 + h*48 + a*16 + 8);
      *(u16x8*)(Vp + dst + a*16) = va;
      *(u16x8*)(Vp + dst + a*16 + 8) = vb;
    }
    *(u16x8*)(Qp + dst + 48) = zz; *(u16x8*)(Qp + dst + 56) = zz;
    *(u16x8*)(Kp + dst + 48) = zz; *(u16x8*)(Kp + dst + 56) = zz;
    *(u16x8*)(Vp + dst + 48) = zz; *(u16x8*)(Vp + dst + 56) = zz;
  }
}

// ---------------- V transpose to (h, w, d64, k1024) ----------------
__global__ __launch_bounds__(256) void vtrans_kernel(const u16* __restrict__ Vp, u16* __restrict__ Vt, int N)
{
  __shared__ u16 tl[64][65];
  int nkb = N>>6;
  int h = blockIdx.x / nkb;
  int k0 = (blockIdx.x % nkb)<<6;
  int t=threadIdx.x;
  #pragma unroll
  for (int p=0;p<16;p++){
    int rr = p*4 + (t>>6);
    tl[rr][t&63] = Vp[((size_t)h*N + k0 + rr)*64 + (t&63)];
  }
  __syncthreads();
  int w = k0>>10; int kw0 = k0 & 1023; int nw = N>>10;
  #pragma unroll
  for (int p=0;p<16;p++){
    int dd = p*4 + (t>>6);
    Vt[(((size_t)h*nw + w)*64 + dd)*1024 + kw0 + (t&63)] = tl[t&63][dd];
  }
}

// ---------------- windowed attention: flash-style, two-pass softmax ----------------
// block = (h, w, qc): 512 threads = 8 waves, 32 q-rows/wave, window = 1024 keys.
// S^T via mfma(K, Q) -> lane owns q-column; softmax fully in-register.
#define ATTN_SCALE 0.14433756729740643f
#define KSTRIDE 68

__global__ __launch_bounds__(512) void attn2_kernel(const u16* __restrict__ Qp, const u16* __restrict__ Kp,
    const u16* __restrict__ Vt, const int* __restrict__ order, u16* __restrict__ attn, int N, int nw)
{
  __shared__ u16 Kl[64*KSTRIDE];       // [key64][d64] stride 68
  __shared__ u16 Vl[48*KSTRIDE];       // [d48][key64] stride 68
  __shared__ u16 Pl[8][32*KSTRIDE];    // per-wave P [q32][key64] stride 68
  __shared__ float lbuf[8][32];
  int b = blockIdx.x;
  int qc = b & 3;
  int hw = b >> 2;
  int w = hw % nw, h = hw / nw;
  int t = threadIdx.x, lane = t&63, wv = t>>6;
  int fr = lane & 15, fg = lane >> 4;     // fragment row, k-group
  size_t base = ((size_t)h*N + (size_t)w*1024);
  size_t vbase = ((size_t)h*nw + w)*64;
  int q0 = qc*256 + wv*32;
  // staging coords
  int srow = t>>3, scol = (t&7)*8;
  const u16* ksrc = Kp + (base + srow)*64 + scol;
  const u16* vsrc = Vt + (vbase + srow)*1024 + scol;
  u16* kdst = Kl + srow*KSTRIDE + scol;
  u16* vdst = Vl + srow*KSTRIDE + scol;
  // Q fragments (B-operand): qf[n][s], n = q 16-block, s = 32-wide k step over d
  s16x8 qf[2][2];
  #pragma unroll
  for (int n=0;n<2;n++)
  #pragma unroll
  for (int s=0;s<2;s++)
    qf[n][s] = *(const s16x8*)(Qp + (base + q0 + n*16 + fr)*64 + s*32 + fg*8);

  // ---- pass 1: exact per-q max ----
  float mx0 = -3.4e38f, mx1 = -3.4e38f;
  for (int c=0;c<16;c++){
    __syncthreads();
    { ux4 dv = *(const ux4*)(ksrc + (size_t)c*64*64);
      u16x4 lo, hi;
      lo[0]=(u16)dv[0]; lo[1]=(u16)(dv[0]>>16); lo[2]=(u16)dv[1]; lo[3]=(u16)(dv[1]>>16);
      hi[0]=(u16)dv[2]; hi[1]=(u16)(dv[2]>>16); hi[2]=(u16)dv[3]; hi[3]=(u16)(dv[3]>>16);
      *(u16x4*)kdst = lo; *(u16x4*)(kdst+4) = hi;
    }
    __syncthreads();
    #pragma unroll
    for (int m=0;m<4;m++){
      fx4 a0 = (fx4){0.f,0.f,0.f,0.f}, a1 = a0;
      #pragma unroll
      for (int s=0;s<2;s++){
        s16x8 af = ld_bf8(Kl + (m*16+fr)*KSTRIDE + s*32 + fg*8);
        a0 = __builtin_amdgcn_mfma_f32_16x16x32_bf16(af, qf[0][s], a0, 0,0,0);
        a1 = __builtin_amdgcn_mfma_f32_16x16x32_bf16(af, qf[1][s], a1, 0,0,0);
      }
      #pragma unroll
      for (int j=0;j<4;j++){ mx0 = fmaxf(mx0, a0[j]); mx1 = fmaxf(mx1, a1[j]); }
    }
  }
  mx0 = fmaxf(mx0, __shfl_xor(mx0,16)); mx0 = fmaxf(mx0, __shfl_xor(mx0,32));
  mx1 = fmaxf(mx1, __shfl_xor(mx1,16)); mx1 = fmaxf(mx1, __shfl_xor(mx1,32));

  // ---- pass 2: exp + PV accumulate ----
  float ls0 = 0.f, ls1 = 0.f;
  fx4 o00=(fx4){0.f,0.f,0.f,0.f}, o01=o00, o02=o00, o10=o00, o11=o00, o12=o00;
  u16* pl = Pl[wv];
  for (int c=0;c<16;c++){
    __syncthreads();
    { ux4 dv = *(const ux4*)(ksrc + (size_t)c*64*64);
      u16x4 lo, hi;
      lo[0]=(u16)dv[0]; lo[1]=(u16)(dv[0]>>16); lo[2]=(u16)dv[1]; lo[3]=(u16)(dv[1]>>16);
      hi[0]=(u16)dv[2]; hi[1]=(u16)(dv[2]>>16); hi[2]=(u16)dv[3]; hi[3]=(u16)(dv[3]>>16);
      *(u16x4*)kdst = lo; *(u16x4*)(kdst+4) = hi;
      if (t < 384){
        ux4 vv = *(const ux4*)(vsrc + (size_t)c*64);
        u16x4 vlo, vhi;
        vlo[0]=(u16)vv[0]; vlo[1]=(u16)(vv[0]>>16); vlo[2]=(u16)vv[1]; vlo[3]=(u16)(vv[1]>>16);
        vhi[0]=(u16)vv[2]; vhi[1]=(u16)(vv[2]>>16); vhi[2]=(u16)vv[3]; vhi[3]=(u16)(vv[3]>>16);
        *(u16x4*)vdst = vlo; *(u16x4*)(vdst+4) = vhi;
      }
    }
    __syncthreads();
    // S^T + P
    #pragma unroll
    for (int m=0;m<4;m++){
      fx4 a0 = (fx4){0.f,0.f,0.f,0.f}, a1 = a0;
      #pragma unroll
      for (int s=0;s<2;s++){
        s16x8 af = ld_bf8(Kl + (m*16+fr)*KSTRIDE + s*32 + fg*8);
        a0 = __builtin_amdgcn_mfma_f32_16x16x32_bf16(af, qf[0][s], a0, 0,0,0);
        a1 = __builtin_amdgcn_mfma_f32_16x16x32_bf16(af, qf[1][s], a1, 0,0,0);
      }
      u16x4 p0, p1;
      #pragma unroll
      for (int j=0;j<4;j++){
        float e0 = __expf((a0[j]-mx0)*ATTN_SCALE);
        float e1 = __expf((a1[j]-mx1)*ATTN_SCALE);
        ls0 += e0; ls1 += e1;
        p0[j] = f2bf(e0); p1[j] = f2bf(e1);
      }
      *(u16x4*)&pl[(fr)*KSTRIDE + m*16 + fg*4]      = p0;
      *(u16x4*)&pl[(16+fr)*KSTRIDE + m*16 + fg*4]   = p1;
    }
    // PV: O[q][d] += P[q][key] * V[key][d]
    #pragma unroll
    for (int s=0;s<2;s++){
      s16x8 pa0 = ld_bf8(pl + fr*KSTRIDE + s*32 + fg*8);
      s16x8 pa1 = ld_bf8(pl + (16+fr)*KSTRIDE + s*32 + fg*8);
      s16x8 vb0 = ld_bf8(Vl + fr*KSTRIDE + s*32 + fg*8);
      s16x8 vb1 = ld_bf8(Vl + (16+fr)*KSTRIDE + s*32 + fg*8);
      s16x8 vb2 = ld_bf8(Vl + (32+fr)*KSTRIDE + s*32 + fg*8);
      o00 = __builtin_amdgcn_mfma_f32_16x16x32_bf16(pa0, vb0, o00, 0,0,0);
      o01 = __builtin_amdgcn_mfma_f32_16x16x32_bf16(pa0, vb1, o01, 0,0,0);
      o02 = __builtin_amdgcn_mfma_f32_16x16x32_bf16(pa0, vb2, o02, 0,0,0);
      o10 = __builtin_amdgcn_mfma_f32_16x16x32_bf16(pa1, vb0, o10, 0,0,0);
      o11 = __builtin_amdgcn_mfma_f32_16x16x32_bf16(pa1, vb1, o11, 0,0,0);
      o12 = __builtin_amdgcn_mfma_f32_16x16x32_bf16(pa1, vb2, o12, 0,0,0);
    }
  }
  // per-q sums -> lbuf
  ls0 += __shfl_xor(ls0,16); ls0 += __shfl_xor(ls0,32);
  ls1 += __shfl_xor(ls1,16); ls1 += __shfl_xor(ls1,32);
  if (lane < 32) lbuf[wv][lane] = (lane < 16) ? ls0 : ls1;
  // epilogue: scatter to original token rows
  const int* ord = order + w*1024 + q0;
  #pragma unroll
  for (int j=0;j<4;j++){
    int qr0 = fg*4 + j;
    float inv0 = 1.0f / lbuf[wv][qr0];
    int orig0 = ord[qr0];
    u16* dst0 = attn + (size_t)orig0*384 + h*48;
    dst0[fr]      = f2bf(o00[j]*inv0);
    dst0[16+fr]   = f2bf(o01[j]*inv0);
    dst0[32+fr]   = f2bf(o02[j]*inv0);
    int qr1 = 16 + fg*4 + j;
    float inv1 = 1.0f / lbuf[wv][qr1];
    int orig1 = ord[qr1];
    u16* dst1 = attn + (size_t)orig1*384 + h*48;
    dst1[fr]      = f2bf(o10[j]*inv1);
    dst1[16+fr]   = f2bf(o11[j]*inv1);
    dst1[32+fr]   = f2bf(o12[j]*inv1);
  }
}

// ---------------- LN2 (row-major input) ----------------
__global__ __launch_bounds__(256) void ln2_kernel(const float* __restrict__ y, const float* __restrict__ g,
    const float* __restrict__ b, u16* __restrict__ out, int N)
{
  int tok = (blockIdx.x<<2) + (threadIdx.x>>6);
  int lane = threadIdx.x & 63;
  const float* row = y + (size_t)tok*384;
  float v[6];
  #pragma unroll
  for (int j=0;j<6;j++) v[j] = row[lane + 64*j];
  float s = 0.f;
  #pragma unroll
  for (int j=0;j<6;j++) s += v[j];
  #pragma unroll
  for (int m=1;m<64;m<<=1) s += __shfl_xor(s,m);
  float mu = s*(1.0f/384.0f);
  float vr = 0.f;
  #pragma unroll
  for (int j=0;j<6;j++){ float d=v[j]-mu; vr += d*d; }
  #pragma unroll
  for (int m=1;m<64;m<<=1) vr += __shfl_xor(vr,m);
  float rs = rsqrtf(vr*(1.0f/384.0f) + 1e-5f);
  u16* dst = out + (size_t)tok*384;
  #pragma unroll
  for (int j=0;j<6;j++){
    int c = lane + 64*j;
    dst[c] = f2bf((v[j]-mu)*rs*g[c] + b[c]);
  }
}

extern "C" void kernel_launch(void* const* d_in, const int* in_sizes, int n_in,
                              void* d_out, int out_size, void* d_ws, size_t ws_size,
                              hipStream_t stream)
{
  (void)n_in; (void)out_size; (void)ws_size;
  const float* x     = (const float*)d_in[0];
  const float* xyz   = (const float*)d_in[1];
  const float* ln1_g = (const float*)d_in[2];
  const float* ln1_b = (const float*)d_in[3];
  const float* qkv_w = (const float*)d_in[4];
  const float* qkv_b = (const float*)d_in[5];
  const float* proj_w= (const float*)d_in[6];
  const float* proj_b= (const float*)d_in[7];
  const float* ln2_g = (const float*)d_in[8];
  const float* ln2_b = (const float*)d_in[9];
  const float* ffn_w1= (const float*)d_in[10];
  const float* ffn_b1= (const float*)d_in[11];
  const float* ffn_w2= (const float*)d_in[12];
  const float* ffn_b2= (const float*)d_in[13];
  int N = in_sizes[0]/384;
  int nw = N/1024;
  char* wsp = (char*)d_ws;
  size_t off = 0;
  auto alloc = [&](size_t bytes)->char*{ char* p = wsp + off; off = (off + bytes + 255) & ~(size_t)255; return p; };
  int*  order   = (int*)alloc((size_t)N*4);
  int*  gridS   = (int*)alloc((size_t)N*12);
  int*  gridO   = (int*)alloc((size_t)N*12);
  u64*  keysA   = (u64*)alloc((size_t)N*8);
  u64*  keysB   = (u64*)alloc((size_t)N*8);
  u16*  qkv_wT  = (u16*)alloc((size_t)1152*384*2);
  u16*  proj_wT = (u16*)alloc((size_t)384*384*2);
  u16*  w1T     = (u16*)alloc((size_t)1536*384*2);
  u16*  w2T     = (u16*)alloc((size_t)384*1536*2);
  u16*  xn      = (u16*)alloc((size_t)N*384*2);
  u16*  qkvb    = (u16*)alloc((size_t)N*1152*2);
  u16*  Qp      = (u16*)alloc((size_t)N*64*8*2);
  u16*  Kp      = (u16*)alloc((size_t)N*64*8*2);
  u16*  Vp      = (u16*)alloc((size_t)N*64*8*2);
  u16*  Vt      = (u16*)alloc((size_t)N*64*8*2);
  float* y1     = (float*)alloc((size_t)N*384*4);
  u16*  attn    = xn;     // xn dead after QKV gemm
  u16*  xn2     = qkvb;   // qkvb dead after rope_kernel
  u16*  mid     = Qp;     // Qp/Kp/Vp dead after attention; N*1536*2 == 3*(N*64*8*2)
  float* outF = (float*)d_out;

  // ---- parallel Z-order sort: keys -> 2048-run bitonic -> 3 merge rounds -> finalize ----
  keys_init_kernel<<<1, 1024, 0, stream>>>(xyz, keysA, gridO, N);
  bsort_kernel<<<N/2048, 1024, 0, stream>>>(keysA);
  merge_kernel<<<N/2048, 256, 0, stream>>>(keysA, keysB, 2048, N);
  merge_kernel<<<N/2048, 256, 0, stream>>>(keysB, keysA, 4096, N);
  merge_kernel<<<N/2048, 256, 0, stream>>>(keysA, keysB, 8192, N);
  finalize_kernel<<<N/256, 256, 0, stream>>>(keysB, gridO, order, gridS, N);

  wtrans_kernel<<<(1152/32)*(384/32), 256, 0, stream>>>(qkv_w, qkv_wT, 384, 1152);
  wtrans_kernel<<<(384/32)*(384/32), 256, 0, stream>>>(proj_w, proj_wT, 384, 384);
  wtrans_kernel<<<(1536/32)*(384/32), 256, 0, stream>>>(ffn_w1, w1T, 384, 1536);
  wtrans_kernel<<<(384/32)*(1536/32), 256, 0, stream>>>(ffn_w2, w2T, 1536, 384);
  ln1_kernel<<<N/64, 256, 64*388*4, stream>>>(x, ln1_g, ln1_b, xn, N);
  gemm_kernel<0><<<(N/64)*(1152/64), 256, 0, stream>>>(xn, qkv_wT, qkv_b, qkvb, nullptr, nullptr, N, 1152, 384);
  rope_kernel<<<N/64, 256, 0, stream>>>(qkvb, order, gridS, Qp, Kp, Vp, N);
  vtrans_kernel<<<8*(N/64), 256, 0, stream>>>(Vp, Vt, N);
  attn2_kernel<<<8*nw*4, 512, 0, stream>>>(Qp, Kp, Vt, order, attn, N, nw);
  gemm_kernel<2><<<(N/64)*(384/64), 256, 0, stream>>>(attn, proj_wT, proj_b, nullptr, y1, x, N, 384, 384);
  ln2_kernel<<<N/4, 256, 0, stream>>>(y1, ln2_g, ln2_b, xn2, N);
  gemm_kernel<1><<<(N/64)*(1536/64), 256, 0, stream>>>(xn2, w1T, ffn_b1, mid, nullptr, nullptr, N, 1536, 384);
  gemm_kernel<3><<<(N/64)*(384/64), 256, 0, stream>>>(mid, w2T, ffn_b2, nullptr, outF, y1, N, 384, 1536);
}

// Round 4
// 344.715 us; speedup vs baseline: 5.5777x; 1.0711x over previous
//
#include <hip/hip_runtime.h>
#include <hip/hip_bf16.h>

typedef unsigned short u16;
typedef unsigned int u32;
typedef unsigned long long u64;
typedef __attribute__((ext_vector_type(8))) short s16x8;
typedef __attribute__((ext_vector_type(4))) short s16x4;
typedef __attribute__((ext_vector_type(8))) unsigned short u16x8;
typedef __attribute__((ext_vector_type(4))) unsigned short u16x4;
typedef __attribute__((ext_vector_type(4))) float fx4;
typedef __attribute__((ext_vector_type(4))) unsigned int ux4;

__device__ __forceinline__ float bf2f(u16 u){ u32 x=((u32)u)<<16; return __builtin_bit_cast(float,x); }
__device__ __forceinline__ u16 f2bf(float f){ u32 x=__builtin_bit_cast(u32,f); return (u16)((x + 0x7FFFu + ((x>>16)&1u))>>16); }

__device__ __forceinline__ s16x8 ld_bf8(const u16* p){
  s16x4 lo = *(const s16x4*)p;
  s16x4 hi = *(const s16x4*)(p+4);
  s16x8 r;
  r[0]=lo[0]; r[1]=lo[1]; r[2]=lo[2]; r[3]=lo[3];
  r[4]=hi[0]; r[5]=hi[1]; r[6]=hi[2]; r[7]=hi[3];
  return r;
}

// async global->LDS, 16B per lane; LDS dest = wave-uniform base + lane*16
__device__ __forceinline__ void gload16(const void* g, void* l){
  __builtin_amdgcn_global_load_lds((__attribute__((address_space(1))) void*)g,
                                   (__attribute__((address_space(3))) void*)l, 16, 0, 0);
}

__device__ __forceinline__ u64 spread3(u32 v){
  u64 x = v & 0xFFFFull;
  x = (x | (x<<32)) & 0x001f00000000ffffull;
  x = (x | (x<<16)) & 0x001f0000ff0000ffull;
  x = (x | (x<<8))  & 0x100f00f00f00f00full;
  x = (x | (x<<4))  & 0x10c30c30c30c30c3ull;
  x = (x | (x<<2))  & 0x1249249249249249ull;
  return x;
}

// ---------------- sort stage 1: mins + keys + grid coords (original order) ----------------
__global__ __launch_bounds__(1024) void keys_init_kernel(const float* __restrict__ xyz,
        u64* __restrict__ keys, int* __restrict__ gridO, int N)
{
  __shared__ float red[3][16];
  __shared__ float mnS[3];
  int t = threadIdx.x; int lane = t&63; int wv = t>>6;
  float m0=3.4e38f,m1=3.4e38f,m2=3.4e38f;
  for (int i=t;i<N;i+=1024){
    m0=fminf(m0,xyz[i]); m1=fminf(m1,xyz[N+i]); m2=fminf(m2,xyz[2*N+i]);
  }
  for (int s=1;s<64;s<<=1){
    m0=fminf(m0,__shfl_xor(m0,s));
    m1=fminf(m1,__shfl_xor(m1,s));
    m2=fminf(m2,__shfl_xor(m2,s));
  }
  if (lane==0){ red[0][wv]=m0; red[1][wv]=m1; red[2][wv]=m2; }
  __syncthreads();
  if (t<3){ float m=red[t][0]; for(int i=1;i<16;i++) m=fminf(m,red[t][i]); mnS[t]=m; }
  __syncthreads();
  float mx0=mnS[0],mx1=mnS[1],mx2=mnS[2];
  for (int i=t;i<N;i+=1024){
    int gx=(int)((xyz[i]-mx0)/0.02f);     gx = gx<0?0:(gx>65535?65535:gx);
    int gy=(int)((xyz[N+i]-mx1)/0.02f);   gy = gy<0?0:(gy>65535?65535:gy);
    int gz=(int)((xyz[2*N+i]-mx2)/0.02f); gz = gz<0?0:(gz>65535?65535:gz);
    gridO[i*3+0]=gx; gridO[i*3+1]=gy; gridO[i*3+2]=gz;
    u64 mort = (spread3((u32)gx)<<2)|(spread3((u32)gy)<<1)|spread3((u32)gz);
    keys[i] = (mort<<14) | (u64)i;   // stable tie-break = ascending index
  }
}

// ---------------- sort stage 2: bitonic sort 2048-key runs in LDS ----------------
__global__ __launch_bounds__(1024) void bsort_kernel(u64* __restrict__ keys)
{
  __shared__ u64 sk[2048];
  int t = threadIdx.x;
  u64* base = keys + (size_t)blockIdx.x*2048;
  sk[t] = base[t]; sk[t+1024] = base[t+1024];
  for (int size=2; size<=2048; size<<=1){
    for (int stride=size>>1; stride>0; stride>>=1){
      __syncthreads();
      int i = 2*t - (t & (stride-1));
      int j = i + stride;
      u64 a = sk[i], b = sk[j];
      bool up = ((i & size) == 0);
      if ((a > b) == up){ sk[i]=b; sk[j]=a; }
    }
  }
  __syncthreads();
  base[t] = sk[t]; base[t+1024] = sk[t+1024];
}

// ---------------- sort stage 3: merge-path pairwise merge (runs of length L) ----------------
__global__ __launch_bounds__(256) void merge_kernel(const u64* __restrict__ src, u64* __restrict__ dst,
        int L, int N)
{
  int gt = blockIdx.x*256 + threadIdx.x;
  int d0 = gt*8;
  if (d0 >= N) return;
  int pair = d0 / (2*L);
  int base = pair*2*L;
  int ld = d0 - base;
  const u64* A = src + base;
  const u64* B = A + L;
  int lo = ld > L ? ld - L : 0;
  int hi = ld < L ? ld : L;
  while (lo < hi){
    int mid = (lo+hi)>>1;
    if (A[mid] <= B[ld-1-mid]) lo = mid+1; else hi = mid;
  }
  int i = lo, j = ld - lo;
  u64* out = dst + base + ld;
  u64 a = (i < L) ? A[i] : ~0ull;
  u64 b = (j < L) ? B[j] : ~0ull;
  #pragma unroll
  for (int e=0;e<8;e++){
    if (a <= b){ out[e] = a; i++; a = (i<L)?A[i]:~0ull; }
    else       { out[e] = b; j++; b = (j<L)?B[j]:~0ull; }
  }
}

// ---------------- sort stage 4: write order + gather grid coords to sorted order ----------------
__global__ __launch_bounds__(256) void finalize_kernel(const u64* __restrict__ keys, const int* __restrict__ gridO,
        int* __restrict__ order, int* __restrict__ gridS, int N)
{
  int i = blockIdx.x*256 + threadIdx.x;
  if (i >= N) return;
  int orig = (int)(keys[i] & 16383ull);
  order[i] = orig;
  gridS[i*3+0] = gridO[orig*3+0];
  gridS[i*3+1] = gridO[orig*3+1];
  gridS[i*3+2] = gridO[orig*3+2];
}

// ---------------- all 4 weight transposes -> bf16 (Nout, K), one launch ----------------
__global__ __launch_bounds__(256) void wtrans4_kernel(const float* __restrict__ qkv_w, const float* __restrict__ proj_w,
    const float* __restrict__ w1, const float* __restrict__ w2,
    u16* __restrict__ qkv_wT, u16* __restrict__ proj_wT, u16* __restrict__ w1T, u16* __restrict__ w2T)
{
  __shared__ float tl[32][33];
  int bid = blockIdx.x;
  const float* W; u16* Wt; int K, Nc, lb;
  if (bid < 432)      { W=qkv_w;  Wt=qkv_wT;  K=384;  Nc=1152; lb=bid; }
  else if (bid < 576) { W=proj_w; Wt=proj_wT; K=384;  Nc=384;  lb=bid-432; }
  else if (bid < 1152){ W=w1;     Wt=w1T;     K=384;  Nc=1536; lb=bid-576; }
  else                { W=w2;     Wt=w2T;     K=1536; Nc=384;  lb=bid-1152; }
  int nb = Nc/32;
  int n0 = (lb % nb)*32;
  int k0 = (lb / nb)*32;
  int t=threadIdx.x; int r=t>>5, c=t&31;
  #pragma unroll
  for (int p=0;p<4;p++) tl[p*8+r][c] = W[(size_t)(k0+p*8+r)*Nc + n0+c];
  __syncthreads();
  #pragma unroll
  for (int p=0;p<4;p++) Wt[(size_t)(n0+p*8+r)*K + k0+c] = f2bf(tl[c][p*8+r]);
}

// ---------------- LN fused with (C,N)->(N,C) transpose (used for LN1 and LN2) ----------------
__global__ __launch_bounds__(256) void ln1_kernel(const float* __restrict__ x, const float* __restrict__ g,
     const float* __restrict__ b, u16* __restrict__ xn, int N)
{
  extern __shared__ char dsm[];
  float* tile = (float*)dsm; // [64][388]
  int n0 = blockIdx.x*64;
  int t = threadIdx.x;
  #pragma unroll 4
  for (int p=0;p<96;p++){
    int cc = p*4 + (t>>6);
    tile[(t&63)*388 + cc] = x[(size_t)cc*N + n0 + (t&63)];
  }
  __syncthreads();
  int tok = t>>2, part = t&3;
  const float* row = tile + tok*388 + part*96;
  float s=0.f;
  #pragma unroll
  for (int j=0;j<96;j++) s += row[j];
  s += __shfl_xor(s,1); s += __shfl_xor(s,2);
  float mu = s*(1.0f/384.0f);
  float vr=0.f;
  #pragma unroll
  for (int j=0;j<96;j++){ float d=row[j]-mu; vr += d*d; }
  vr += __shfl_xor(vr,1); vr += __shfl_xor(vr,2);
  float rs = rsqrtf(vr*(1.0f/384.0f) + 1e-5f);
  u16* dst = xn + (size_t)(n0+tok)*384 + part*96;
  #pragma unroll
  for (int q=0;q<12;q++){
    u16x8 o;
    #pragma unroll
    for (int j=0;j<8;j++){
      int c = part*96 + q*8 + j;
      o[j] = f2bf((row[q*8+j]-mu)*rs*g[c] + b[c]);
    }
    *(u16x8*)(dst + q*8) = o;
  }
}

// ---------------- 128x128 MFMA GEMM (m97 structure) with fused epilogues ----------------
__device__ __forceinline__ float gelu_f(float v){
  return 0.5f*v*(1.0f + erff(v*0.7071067811865475f));
}

// EPI 0: outB bf16 = acc+bias                         (QKV)
// EPI 1: outB bf16 = gelu(acc+bias)                   (FFN1)
// EPI 2: outF f32 (C,M) transposed float4 store = acc+bias+res[(c)*M+m]   (proj->y1 res=x, FFN2->d_out res=y1)
template<int EPI>
__global__ __launch_bounds__(256) void gemm128_kernel(const u16* __restrict__ A, const u16* __restrict__ Bt,
    const float* __restrict__ bias, u16* __restrict__ outB, float* __restrict__ outF,
    const float* __restrict__ res, int M, int Nout, int K)
{
  __shared__ u16 Al[128*32];
  __shared__ u16 Bl[128*32];
  int nb = Nout>>7;
  int m0 = (blockIdx.x/nb)<<7;
  int n0 = (blockIdx.x%nb)<<7;
  int t = threadIdx.x, lane=t&63, wv=t>>6, wr=wv>>1, wc=wv&1;
  int fr = lane&15, fg = lane>>4;
  fx4 acc[4][4];
  #pragma unroll
  for (int i=0;i<4;i++)
  #pragma unroll
  for (int j=0;j<4;j++) acc[i][j]=(fx4){0.f,0.f,0.f,0.f};
  // staging: per wave 2 issues of 1024B per matrix; lane covers 16B
  int srow = wv*32 + (lane>>2);          // +16 for second issue
  int scol = (lane&3)*8;
  const u16* ApL = A  + (size_t)(m0+srow)*K + scol;
  const u16* BpL = Bt + (size_t)(n0+srow)*K + scol;
  u16* AlW = Al + wv*1024 + lane*8;      // = wave base + lane*16B (linear)
  u16* BlW = Bl + wv*1024 + lane*8;
  const u16* a_rd = Al + (wr*64+fr)*32 + fg*8;
  const u16* b_rd = Bl + (wc*64+fr)*32 + fg*8;
  for (int k0=0;k0<K;k0+=32){
    gload16(ApL+k0,        AlW);
    gload16(ApL+k0+16*K,   AlW+512);
    gload16(BpL+k0,        BlW);
    gload16(BpL+k0+16*K,   BlW+512);
    __syncthreads();                      // drains vmcnt -> tile resident
    s16x8 a[4], b[4];
    #pragma unroll
    for (int mi=0;mi<4;mi++) a[mi] = *(const s16x8*)(a_rd + mi*16*32);
    #pragma unroll
    for (int ni=0;ni<4;ni++) b[ni] = *(const s16x8*)(b_rd + ni*16*32);
    #pragma unroll
    for (int mi=0;mi<4;mi++)
    #pragma unroll
    for (int ni=0;ni<4;ni++)
      acc[mi][ni] = __builtin_amdgcn_mfma_f32_16x16x32_bf16(a[mi], b[ni], acc[mi][ni], 0,0,0);
    __syncthreads();                      // all reads done before next overwrite
  }
  if (EPI==0 || EPI==1){
    #pragma unroll
    for (int mi=0;mi<4;mi++)
    #pragma unroll
    for (int ni=0;ni<4;ni++){
      int c = n0 + wc*64 + ni*16 + fr;
      float bi = bias[c];
      int mb = m0 + wr*64 + mi*16 + fg*4;
      #pragma unroll
      for (int j=0;j<4;j++){
        float vv = acc[mi][ni][j] + bi;
        if (EPI==1) vv = gelu_f(vv);
        outB[(size_t)(mb+j)*Nout + c] = f2bf(vv);
      }
    }
  } else {
    #pragma unroll
    for (int mi=0;mi<4;mi++)
    #pragma unroll
    for (int ni=0;ni<4;ni++){
      int c = n0 + wc*64 + ni*16 + fr;
      float bi = bias[c];
      size_t idx = (size_t)c*M + m0 + wr*64 + mi*16 + fg*4;
      fx4 r4 = *(const fx4*)(res + idx);
      fx4 o;
      #pragma unroll
      for (int j=0;j<4;j++) o[j] = acc[mi][ni][j] + bi + r4[j];
      *(fx4*)(outF + idx) = o;
    }
  }
}

// ---------------- RoPE + gather-into-sorted-window layout ----------------
__global__ __launch_bounds__(256) void rope_kernel(const u16* __restrict__ qkv, const int* __restrict__ order,
    const int* __restrict__ gridS, u16* __restrict__ Qp, u16* __restrict__ Kp, u16* __restrict__ Vp, int N)
{
  __shared__ float csm[64][24][2];
  __shared__ int origs[64];
  int i0 = blockIdx.x<<6;
  int t = threadIdx.x;
  if (t<64) origs[t] = order[i0+t];
  for (int idx=t; idx<64*24; idx+=256){
    int tok = idx/24, slot = idx - tok*24;
    int a = slot>>3, fi = slot&7;
    int pos = gridS[(size_t)(i0+tok)*3 + a];
    pos = pos<0?0:(pos>4095?4095:pos);
    float invf = powf(100.0f, -(float)fi*0.125f);
    float ang = (float)pos * invf;
    csm[tok][slot][0] = cosf(ang);
    csm[tok][slot][1] = sinf(ang);
  }
  __syncthreads();
  int tok = t&63;
  int i = i0 + tok;
  const u16* src = qkv + (size_t)origs[tok]*1152;
  u16x8 zz = {0,0,0,0,0,0,0,0};
  for (int h=t>>6; h<8; h+=4){
    size_t dst = ((size_t)h*N + i)*64;
    #pragma unroll
    for (int a=0;a<3;a++){
      u16x8 qa = *(const u16x8*)(src + h*48 + a*16);
      u16x8 qb = *(const u16x8*)(src + h*48 + a*16 + 8);
      u16x8 ka = *(const u16x8*)(src + 384 + h*48 + a*16);
      u16x8 kb = *(const u16x8*)(src + 384 + h*48 + a*16 + 8);
      u16x8 oqa, oqb, oka, okb;
      #pragma unroll
      for (int j=0;j<8;j++){
        float c0 = csm[tok][a*8+j][0], s0 = csm[tok][a*8+j][1];
        float ql = bf2f(qa[j]), qh = bf2f(qb[j]);
        float kl = bf2f(ka[j]), kh = bf2f(kb[j]);
        oqa[j] = f2bf(ql*c0 - qh*s0);
        oqb[j] = f2bf(qh*c0 + ql*s0);
        oka[j] = f2bf(kl*c0 - kh*s0);
        okb[j] = f2bf(kh*c0 + kl*s0);
      }
      *(u16x8*)(Qp + dst + a*16) = oqa;
      *(u16x8*)(Qp + dst + a*16 + 8) = oqb;
      *(u16x8*)(Kp + dst + a*16) = oka;
      *(u16x8*)(Kp + dst + a*16 + 8) = okb;
      u16x8 va = *(const u16x8*)(src + 768 + h*48 + a*16);
      u16x8 vb = *(const u16x8*)(src + 768 + h*48 + a*16 + 8);
      *(u16x8*)(Vp + dst + a*16) = va;
      *(u16x8*)(Vp + dst + a*16 + 8) = vb;
    }
    *(u16x8*)(Qp + dst + 48) = zz; *(u16x8*)(Qp + dst + 56) = zz;
    *(u16x8*)(Kp + dst + 48) = zz; *(u16x8*)(Kp + dst + 56) = zz;
    *(u16x8*)(Vp + dst + 48) = zz; *(u16x8*)(Vp + dst + 56) = zz;
  }
}

// ---------------- V transpose to (h, w, d64, k1024) ----------------
__global__ __launch_bounds__(256) void vtrans_kernel(const u16* __restrict__ Vp, u16* __restrict__ Vt, int N)
{
  __shared__ u16 tl[64][65];
  int nkb = N>>6;
  int h = blockIdx.x / nkb;
  int k0 = (blockIdx.x % nkb)<<6;
  int t=threadIdx.x;
  #pragma unroll
  for (int p=0;p<16;p++){
    int rr = p*4 + (t>>6);
    tl[rr][t&63] = Vp[((size_t)h*N + k0 + rr)*64 + (t&63)];
  }
  __syncthreads();
  int w = k0>>10; int kw0 = k0 & 1023; int nw = N>>10;
  #pragma unroll
  for (int p=0;p<16;p++){
    int dd = p*4 + (t>>6);
    Vt[(((size_t)h*nw + w)*64 + dd)*1024 + kw0 + (t&63)] = tl[t&63][dd];
  }
}

// ---------------- windowed attention: flash-style, two-pass softmax ----------------
#define ATTN_SCALE 0.14433756729740643f
#define KSTRIDE 68

__global__ __launch_bounds__(512) void attn2_kernel(const u16* __restrict__ Qp, const u16* __restrict__ Kp,
    const u16* __restrict__ Vt, const int* __restrict__ order, u16* __restrict__ attn, int N, int nw)
{
  __shared__ u16 Kl[64*KSTRIDE];       // [key64][d64] stride 68
  __shared__ u16 Vl[48*KSTRIDE];       // [d48][key64] stride 68
  __shared__ u16 Pl[8][32*KSTRIDE];    // per-wave P [q32][key64] stride 68
  __shared__ float lbuf[8][32];
  int b = blockIdx.x;
  int qc = b & 3;
  int hw = b >> 2;
  int w = hw % nw, h = hw / nw;
  int t = threadIdx.x, lane = t&63, wv = t>>6;
  int fr = lane & 15, fg = lane >> 4;
  size_t base = ((size_t)h*N + (size_t)w*1024);
  size_t vbase = ((size_t)h*nw + w)*64;
  int q0 = qc*256 + wv*32;
  int srow = t>>3, scol = (t&7)*8;
  const u16* ksrc = Kp + (base + srow)*64 + scol;
  const u16* vsrc = Vt + (vbase + srow)*1024 + scol;
  u16* kdst = Kl + srow*KSTRIDE + scol;
  u16* vdst = Vl + srow*KSTRIDE + scol;
  s16x8 qf[2][2];
  #pragma unroll
  for (int n=0;n<2;n++)
  #pragma unroll
  for (int s=0;s<2;s++)
    qf[n][s] = *(const s16x8*)(Qp + (base + q0 + n*16 + fr)*64 + s*32 + fg*8);

  // ---- pass 1: exact per-q max ----
  float mx0 = -3.4e38f, mx1 = -3.4e38f;
  for (int c=0;c<16;c++){
    __syncthreads();
    { ux4 dv = *(const ux4*)(ksrc + (size_t)c*64*64);
      u16x4 lo, hi;
      lo[0]=(u16)dv[0]; lo[1]=(u16)(dv[0]>>16); lo[2]=(u16)dv[1]; lo[3]=(u16)(dv[1]>>16);
      hi[0]=(u16)dv[2]; hi[1]=(u16)(dv[2]>>16); hi[2]=(u16)dv[3]; hi[3]=(u16)(dv[3]>>16);
      *(u16x4*)kdst = lo; *(u16x4*)(kdst+4) = hi;
    }
    __syncthreads();
    #pragma unroll
    for (int m=0;m<4;m++){
      fx4 a0 = (fx4){0.f,0.f,0.f,0.f}, a1 = a0;
      #pragma unroll
      for (int s=0;s<2;s++){
        s16x8 af = ld_bf8(Kl + (m*16+fr)*KSTRIDE + s*32 + fg*8);
        a0 = __builtin_amdgcn_mfma_f32_16x16x32_bf16(af, qf[0][s], a0, 0,0,0);
        a1 = __builtin_amdgcn_mfma_f32_16x16x32_bf16(af, qf[1][s], a1, 0,0,0);
      }
      #pragma unroll
      for (int j=0;j<4;j++){ mx0 = fmaxf(mx0, a0[j]); mx1 = fmaxf(mx1, a1[j]); }
    }
  }
  mx0 = fmaxf(mx0, __shfl_xor(mx0,16)); mx0 = fmaxf(mx0, __shfl_xor(mx0,32));
  mx1 = fmaxf(mx1, __shfl_xor(mx1,16)); mx1 = fmaxf(mx1, __shfl_xor(mx1,32));

  // ---- pass 2: exp + PV accumulate ----
  float ls0 = 0.f, ls1 = 0.f;
  fx4 o00=(fx4){0.f,0.f,0.f,0.f}, o01=o00, o02=o00, o10=o00, o11=o00, o12=o00;
  u16* pl = Pl[wv];
  for (int c=0;c<16;c++){
    __syncthreads();
    { ux4 dv = *(const ux4*)(ksrc + (size_t)c*64*64);
      u16x4 lo, hi;
      lo[0]=(u16)dv[0]; lo[1]=(u16)(dv[0]>>16); lo[2]=(u16)dv[1]; lo[3]=(u16)(dv[1]>>16);
      hi[0]=(u16)dv[2]; hi[1]=(u16)(dv[2]>>16); hi[2]=(u16)dv[3]; hi[3]=(u16)(dv[3]>>16);
      *(u16x4*)kdst = lo; *(u16x4*)(kdst+4) = hi;
      if (t < 384){
        ux4 vv = *(const ux4*)(vsrc + (size_t)c*64);
        u16x4 vlo, vhi;
        vlo[0]=(u16)vv[0]; vlo[1]=(u16)(vv[0]>>16); vlo[2]=(u16)vv[1]; vlo[3]=(u16)(vv[1]>>16);
        vhi[0]=(u16)vv[2]; vhi[1]=(u16)(vv[2]>>16); vhi[2]=(u16)vv[3]; vhi[3]=(u16)(vv[3]>>16);
        *(u16x4*)vdst = vlo; *(u16x4*)(vdst+4) = vhi;
      }
    }
    __syncthreads();
    #pragma unroll
    for (int m=0;m<4;m++){
      fx4 a0 = (fx4){0.f,0.f,0.f,0.f}, a1 = a0;
      #pragma unroll
      for (int s=0;s<2;s++){
        s16x8 af = ld_bf8(Kl + (m*16+fr)*KSTRIDE + s*32 + fg*8);
        a0 = __builtin_amdgcn_mfma_f32_16x16x32_bf16(af, qf[0][s], a0, 0,0,0);
        a1 = __builtin_amdgcn_mfma_f32_16x16x32_bf16(af, qf[1][s], a1, 0,0,0);
      }
      u16x4 p0, p1;
      #pragma unroll
      for (int j=0;j<4;j++){
        float e0 = __expf((a0[j]-mx0)*ATTN_SCALE);
        float e1 = __expf((a1[j]-mx1)*ATTN_SCALE);
        ls0 += e0; ls1 += e1;
        p0[j] = f2bf(e0); p1[j] = f2bf(e1);
      }
      *(u16x4*)&pl[(fr)*KSTRIDE + m*16 + fg*4]      = p0;
      *(u16x4*)&pl[(16+fr)*KSTRIDE + m*16 + fg*4]   = p1;
    }
    #pragma unroll
    for (int s=0;s<2;s++){
      s16x8 pa0 = ld_bf8(pl + fr*KSTRIDE + s*32 + fg*8);
      s16x8 pa1 = ld_bf8(pl + (16+fr)*KSTRIDE + s*32 + fg*8);
      s16x8 vb0 = ld_bf8(Vl + fr*KSTRIDE + s*32 + fg*8);
      s16x8 vb1 = ld_bf8(Vl + (16+fr)*KSTRIDE + s*32 + fg*8);
      s16x8 vb2 = ld_bf8(Vl + (32+fr)*KSTRIDE + s*32 + fg*8);
      o00 = __builtin_amdgcn_mfma_f32_16x16x32_bf16(pa0, vb0, o00, 0,0,0);
      o01 = __builtin_amdgcn_mfma_f32_16x16x32_bf16(pa0, vb1, o01, 0,0,0);
      o02 = __builtin_amdgcn_mfma_f32_16x16x32_bf16(pa0, vb2, o02, 0,0,0);
      o10 = __builtin_amdgcn_mfma_f32_16x16x32_bf16(pa1, vb0, o10, 0,0,0);
      o11 = __builtin_amdgcn_mfma_f32_16x16x32_bf16(pa1, vb1, o11, 0,0,0);
      o12 = __builtin_amdgcn_mfma_f32_16x16x32_bf16(pa1, vb2, o12, 0,0,0);
    }
  }
  ls0 += __shfl_xor(ls0,16); ls0 += __shfl_xor(ls0,32);
  ls1 += __shfl_xor(ls1,16); ls1 += __shfl_xor(ls1,32);
  if (lane < 32) lbuf[wv][lane] = (lane < 16) ? ls0 : ls1;
  const int* ord = order + w*1024 + q0;
  #pragma unroll
  for (int j=0;j<4;j++){
    int qr0 = fg*4 + j;
    float inv0 = 1.0f / lbuf[wv][qr0];
    int orig0 = ord[qr0];
    u16* dst0 = attn + (size_t)orig0*384 + h*48;
    dst0[fr]      = f2bf(o00[j]*inv0);
    dst0[16+fr]   = f2bf(o01[j]*inv0);
    dst0[32+fr]   = f2bf(o02[j]*inv0);
    int qr1 = 16 + fg*4 + j;
    float inv1 = 1.0f / lbuf[wv][qr1];
    int orig1 = ord[qr1];
    u16* dst1 = attn + (size_t)orig1*384 + h*48;
    dst1[fr]      = f2bf(o10[j]*inv1);
    dst1[16+fr]   = f2bf(o11[j]*inv1);
    dst1[32+fr]   = f2bf(o12[j]*inv1);
  }
}

extern "C" void kernel_launch(void* const* d_in, const int* in_sizes, int n_in,
                              void* d_out, int out_size, void* d_ws, size_t ws_size,
                              hipStream_t stream)
{
  (void)n_in; (void)out_size; (void)ws_size;
  const float* x     = (const float*)d_in[0];
  const float* xyz   = (const float*)d_in[1];
  const float* ln1_g = (const float*)d_in[2];
  const float* ln1_b = (const float*)d_in[3];
  const float* qkv_w = (const float*)d_in[4];
  const float* qkv_b = (const float*)d_in[5];
  const float* proj_w= (const float*)d_in[6];
  const float* proj_b= (const float*)d_in[7];
  const float* ln2_g = (const float*)d_in[8];
  const float* ln2_b = (const float*)d_in[9];
  const float* ffn_w1= (const float*)d_in[10];
  const float* ffn_b1= (const float*)d_in[11];
  const float* ffn_w2= (const float*)d_in[12];
  const float* ffn_b2= (const float*)d_in[13];
  int N = in_sizes[0]/384;
  int nw = N/1024;
  char* wsp = (char*)d_ws;
  size_t off = 0;
  auto alloc = [&](size_t bytes)->char*{ char* p = wsp + off; off = (off + bytes + 255) & ~(size_t)255; return p; };
  int*  order   = (int*)alloc((size_t)N*4);
  int*  gridS   = (int*)alloc((size_t)N*12);
  int*  gridO   = (int*)alloc((size_t)N*12);
  u64*  keysA   = (u64*)alloc((size_t)N*8);
  u64*  keysB   = (u64*)alloc((size_t)N*8);
  u16*  qkv_wT  = (u16*)alloc((size_t)1152*384*2);
  u16*  proj_wT = (u16*)alloc((size_t)384*384*2);
  u16*  w1T     = (u16*)alloc((size_t)1536*384*2);
  u16*  w2T     = (u16*)alloc((size_t)384*1536*2);
  u16*  xn      = (u16*)alloc((size_t)N*384*2);
  u16*  qkvb    = (u16*)alloc((size_t)N*1152*2);
  u16*  Qp      = (u16*)alloc((size_t)N*64*8*2);
  u16*  Kp      = (u16*)alloc((size_t)N*64*8*2);
  u16*  Vp      = (u16*)alloc((size_t)N*64*8*2);
  u16*  Vt      = (u16*)alloc((size_t)N*64*8*2);
  float* y1     = (float*)alloc((size_t)N*384*4);   // (C, M) layout
  u16*  attn    = xn;     // xn dead after QKV gemm
  u16*  xn2     = qkvb;   // qkvb dead after rope_kernel
  u16*  mid     = Qp;     // Qp/Kp/Vp dead after attention; N*1536*2 == 3*(N*64*8*2)
  float* outF = (float*)d_out;

  // ---- parallel Z-order sort ----
  keys_init_kernel<<<1, 1024, 0, stream>>>(xyz, keysA, gridO, N);
  bsort_kernel<<<N/2048, 1024, 0, stream>>>(keysA);
  merge_kernel<<<N/2048, 256, 0, stream>>>(keysA, keysB, 2048, N);
  merge_kernel<<<N/2048, 256, 0, stream>>>(keysB, keysA, 4096, N);
  merge_kernel<<<N/2048, 256, 0, stream>>>(keysA, keysB, 8192, N);
  finalize_kernel<<<N/256, 256, 0, stream>>>(keysB, gridO, order, gridS, N);

  wtrans4_kernel<<<1728, 256, 0, stream>>>(qkv_w, proj_w, ffn_w1, ffn_w2, qkv_wT, proj_wT, w1T, w2T);
  ln1_kernel<<<N/64, 256, 64*388*4, stream>>>(x, ln1_g, ln1_b, xn, N);
  gemm128_kernel<0><<<(N/128)*(1152/128), 256, 0, stream>>>(xn, qkv_wT, qkv_b, qkvb, nullptr, nullptr, N, 1152, 384);
  rope_kernel<<<N/64, 256, 0, stream>>>(qkvb, order, gridS, Qp, Kp, Vp, N);
  vtrans_kernel<<<8*(N/64), 256, 0, stream>>>(Vp, Vt, N);
  attn2_kernel<<<8*nw*4, 512, 0, stream>>>(Qp, Kp, Vt, order, attn, N, nw);
  // proj: y1 (C,M) = x + (attn @ proj_w + b)^T
  gemm128_kernel<2><<<(N/128)*(384/128), 256, 0, stream>>>(attn, proj_wT, proj_b, nullptr, y1, x, N, 384, 384);
  // LN2 = same column-layout LN+transpose as LN1
  ln1_kernel<<<N/64, 256, 64*388*4, stream>>>(y1, ln2_g, ln2_b, xn2, N);
  gemm128_kernel<1><<<(N/128)*(1536/128), 256, 0, stream>>>(xn2, w1T, ffn_b1, mid, nullptr, nullptr, N, 1536, 384);
  // FFN2: d_out (C,M) = y1 + (mid @ w2 + b2)^T
  gemm128_kernel<2><<<(N/128)*(384/128), 256, 0, stream>>>(mid, w2T, ffn_b2, nullptr, outF, y1, N, 384, 1536);
}

// Round 5
// 328.581 us; speedup vs baseline: 5.8516x; 1.0491x over previous
//
#include <hip/hip_runtime.h>
#include <hip/hip_bf16.h>

typedef unsigned short u16;
typedef unsigned int u32;
typedef unsigned long long u64;
typedef __attribute__((ext_vector_type(8))) short s16x8;
typedef __attribute__((ext_vector_type(4))) short s16x4;
typedef __attribute__((ext_vector_type(8))) unsigned short u16x8;
typedef __attribute__((ext_vector_type(4))) unsigned short u16x4;
typedef __attribute__((ext_vector_type(4))) float fx4;
typedef __attribute__((ext_vector_type(4))) unsigned int ux4;
typedef __attribute__((ext_vector_type(2))) unsigned int ux2;

__device__ __forceinline__ float bf2f(u16 u){ u32 x=((u32)u)<<16; return __builtin_bit_cast(float,x); }
__device__ __forceinline__ u16 f2bf(float f){ u32 x=__builtin_bit_cast(u32,f); return (u16)((x + 0x7FFFu + ((x>>16)&1u))>>16); }

__device__ __forceinline__ s16x8 ld_bf8(const u16* p){
  s16x4 lo = *(const s16x4*)p;
  s16x4 hi = *(const s16x4*)(p+4);
  s16x8 r;
  r[0]=lo[0]; r[1]=lo[1]; r[2]=lo[2]; r[3]=lo[3];
  r[4]=hi[0]; r[5]=hi[1]; r[6]=hi[2]; r[7]=hi[3];
  return r;
}

// async global->LDS, 16B per lane; LDS dest must be wave-uniform base + lane*16
__device__ __forceinline__ void gload16(const void* g, void* l){
  __builtin_amdgcn_global_load_lds((__attribute__((address_space(1))) void*)g,
                                   (__attribute__((address_space(3))) void*)l, 16, 0, 0);
}

__device__ __forceinline__ u64 spread3(u32 v){
  u64 x = v & 0xFFFFull;
  x = (x | (x<<32)) & 0x001f00000000ffffull;
  x = (x | (x<<16)) & 0x001f0000ff0000ffull;
  x = (x | (x<<8))  & 0x100f00f00f00f00full;
  x = (x | (x<<4))  & 0x10c30c30c30c30c3ull;
  x = (x | (x<<2))  & 0x1249249249249249ull;
  return x;
}

// ---------------- sort stage 0: parallel per-axis min via atomicMin on float bits ----------------
__global__ __launch_bounds__(256) void min3_kernel(const float* __restrict__ xyz, u32* __restrict__ mins, int N)
{
  int i = blockIdx.x*256 + threadIdx.x;
  float v0 = xyz[i], v1 = xyz[N+i], v2 = xyz[2*N+i];
  #pragma unroll
  for (int s=1;s<64;s<<=1){
    v0 = fminf(v0, __shfl_xor(v0,s));
    v1 = fminf(v1, __shfl_xor(v1,s));
    v2 = fminf(v2, __shfl_xor(v2,s));
  }
  if ((threadIdx.x & 63) == 0){
    atomicMin(mins+0, __builtin_bit_cast(u32, v0));
    atomicMin(mins+1, __builtin_bit_cast(u32, v1));
    atomicMin(mins+2, __builtin_bit_cast(u32, v2));
  }
}

// ---------------- sort stage 1: keys + grid coords (original order) ----------------
__global__ __launch_bounds__(256) void keys_grid_kernel(const float* __restrict__ xyz, const u32* __restrict__ mins,
        u64* __restrict__ keys, int* __restrict__ gridO, int N)
{
  int i = blockIdx.x*256 + threadIdx.x;
  float mx0 = __builtin_bit_cast(float, mins[0]);
  float mx1 = __builtin_bit_cast(float, mins[1]);
  float mx2 = __builtin_bit_cast(float, mins[2]);
  int gx=(int)((xyz[i]-mx0)/0.02f);     gx = gx<0?0:(gx>65535?65535:gx);
  int gy=(int)((xyz[N+i]-mx1)/0.02f);   gy = gy<0?0:(gy>65535?65535:gy);
  int gz=(int)((xyz[2*N+i]-mx2)/0.02f); gz = gz<0?0:(gz>65535?65535:gz);
  gridO[i*3+0]=gx; gridO[i*3+1]=gy; gridO[i*3+2]=gz;
  u64 mort = (spread3((u32)gx)<<2)|(spread3((u32)gy)<<1)|spread3((u32)gz);
  keys[i] = (mort<<14) | (u64)i;   // stable tie-break = ascending index
}

// ---------------- sort stage 2: bitonic sort 2048-key runs in LDS ----------------
__global__ __launch_bounds__(1024) void bsort_kernel(u64* __restrict__ keys)
{
  __shared__ u64 sk[2048];
  int t = threadIdx.x;
  u64* base = keys + (size_t)blockIdx.x*2048;
  sk[t] = base[t]; sk[t+1024] = base[t+1024];
  for (int size=2; size<=2048; size<<=1){
    for (int stride=size>>1; stride>0; stride>>=1){
      __syncthreads();
      int i = 2*t - (t & (stride-1));
      int j = i + stride;
      u64 a = sk[i], b = sk[j];
      bool up = ((i & size) == 0);
      if ((a > b) == up){ sk[i]=b; sk[j]=a; }
    }
  }
  __syncthreads();
  base[t] = sk[t]; base[t+1024] = sk[t+1024];
}

// ---------------- sort stage 3: merge-path pairwise merge; FINAL also emits order ----------------
template<bool FINAL>
__global__ __launch_bounds__(256) void merge_kernel(const u64* __restrict__ src, u64* __restrict__ dst,
        int* __restrict__ order, int L, int N)
{
  int gt = blockIdx.x*256 + threadIdx.x;
  int d0 = gt*8;
  if (d0 >= N) return;
  int pair = d0 / (2*L);
  int base = pair*2*L;
  int ld = d0 - base;
  const u64* A = src + base;
  const u64* B = A + L;
  int lo = ld > L ? ld - L : 0;
  int hi = ld < L ? ld : L;
  while (lo < hi){
    int mid = (lo+hi)>>1;
    if (A[mid] <= B[ld-1-mid]) lo = mid+1; else hi = mid;
  }
  int i = lo, j = ld - lo;
  u64* out = dst + base + ld;
  int* oout = order + base + ld;
  u64 a = (i < L) ? A[i] : ~0ull;
  u64 b = (j < L) ? B[j] : ~0ull;
  #pragma unroll
  for (int e=0;e<8;e++){
    u64 v;
    if (a <= b){ v = a; i++; a = (i<L)?A[i]:~0ull; }
    else       { v = b; j++; b = (j<L)?B[j]:~0ull; }
    out[e] = v;
    if (FINAL) oout[e] = (int)(v & 16383ull);
  }
}

// ---------------- all 4 weight transposes -> bf16 (Nout, K), one launch ----------------
__global__ __launch_bounds__(256) void wtrans4_kernel(const float* __restrict__ qkv_w, const float* __restrict__ proj_w,
    const float* __restrict__ w1, const float* __restrict__ w2,
    u16* __restrict__ qkv_wT, u16* __restrict__ proj_wT, u16* __restrict__ w1T, u16* __restrict__ w2T)
{
  __shared__ float tl[32][33];
  int bid = blockIdx.x;
  const float* W; u16* Wt; int K, Nc, lb;
  if (bid < 432)      { W=qkv_w;  Wt=qkv_wT;  K=384;  Nc=1152; lb=bid; }
  else if (bid < 576) { W=proj_w; Wt=proj_wT; K=384;  Nc=384;  lb=bid-432; }
  else if (bid < 1152){ W=w1;     Wt=w1T;     K=384;  Nc=1536; lb=bid-576; }
  else                { W=w2;     Wt=w2T;     K=1536; Nc=384;  lb=bid-1152; }
  int nb = Nc/32;
  int n0 = (lb % nb)*32;
  int k0 = (lb / nb)*32;
  int t=threadIdx.x; int r=t>>5, c=t&31;
  #pragma unroll
  for (int p=0;p<4;p++) tl[p*8+r][c] = W[(size_t)(k0+p*8+r)*Nc + n0+c];
  __syncthreads();
  #pragma unroll
  for (int p=0;p<4;p++) Wt[(size_t)(n0+p*8+r)*K + k0+c] = f2bf(tl[c][p*8+r]);
}

// ---------------- LN fused with (C,N)->(N,C) transpose, 32-token tiles ----------------
__global__ __launch_bounds__(256) void ln32_kernel(const float* __restrict__ x, const float* __restrict__ g,
     const float* __restrict__ b, u16* __restrict__ xn, int N)
{
  extern __shared__ char dsm[];
  float* tile = (float*)dsm; // [32][388]
  int n0 = blockIdx.x*32;
  int t = threadIdx.x;
  int tok32 = t&31, cg = t>>5;
  #pragma unroll 8
  for (int p=0;p<48;p++){
    int cc = p*8 + cg;
    tile[tok32*388 + cc] = x[(size_t)cc*N + n0 + tok32];
  }
  __syncthreads();
  int tok = t>>3, part = t&7;
  const float* row = tile + tok*388 + part*48;
  float s=0.f;
  #pragma unroll
  for (int j=0;j<48;j++) s += row[j];
  s += __shfl_xor(s,1); s += __shfl_xor(s,2); s += __shfl_xor(s,4);
  float mu = s*(1.0f/384.0f);
  float vr=0.f;
  #pragma unroll
  for (int j=0;j<48;j++){ float d=row[j]-mu; vr += d*d; }
  vr += __shfl_xor(vr,1); vr += __shfl_xor(vr,2); vr += __shfl_xor(vr,4);
  float rs = rsqrtf(vr*(1.0f/384.0f) + 1e-5f);
  u16* dst = xn + (size_t)(n0+tok)*384 + part*48;
  #pragma unroll
  for (int q=0;q<6;q++){
    u16x8 o;
    #pragma unroll
    for (int j=0;j<8;j++){
      int c = part*48 + q*8 + j;
      o[j] = f2bf((row[q*8+j]-mu)*rs*g[c] + b[c]);
    }
    *(u16x8*)(dst + q*8) = o;
  }
}

// ---------------- 128x128 MFMA GEMM, BK=64, source-swizzled LDS ----------------
__device__ __forceinline__ float gelu_f(float v){
  return 0.5f*v*(1.0f + erff(v*0.7071067811865475f));
}

// EPI 0: outB bf16 = acc+bias                         (QKV)
// EPI 1: outB bf16 = gelu(acc+bias)                   (FFN1)
// EPI 2: outF f32 (C,M) transposed float4 store = acc+bias+res[c*M+m]   (proj->y1 res=x, FFN2->d_out res=y1)
template<int EPI>
__global__ __launch_bounds__(256) void gemm128_kernel(const u16* __restrict__ A, const u16* __restrict__ Bt,
    const float* __restrict__ bias, u16* __restrict__ outB, float* __restrict__ outF,
    const float* __restrict__ res, int M, int Nout, int K)
{
  __shared__ u16 Al[128*64];
  __shared__ u16 Bl[128*64];
  int nb = Nout>>7;
  int m0 = (blockIdx.x/nb)<<7;
  int n0 = (blockIdx.x%nb)<<7;
  int t = threadIdx.x, lane=t&63, wv=t>>6, wr=wv>>1, wc=wv&1;
  int fr = lane&15, fg = lane>>4;
  fx4 acc[4][4];
  #pragma unroll
  for (int i=0;i<4;i++)
  #pragma unroll
  for (int j=0;j<4;j++) acc[i][j]=(fx4){0.f,0.f,0.f,0.f};
  // staging: row = wv*32 + i*8 + (lane>>3); global col pre-swizzled so LDS slot s holds global slot s^(row&7)
  int srow = wv*32 + (lane>>3);
  int swz  = ((lane&7) ^ ((lane>>3)&7)) * 8;       // u16 col
  const u16* ApL = A  + (size_t)(m0+srow)*K + swz;
  const u16* BpL = Bt + (size_t)(n0+srow)*K + swz;
  u16* AlW = Al + wv*2048 + lane*8;                // bytes: wv*4096 + lane*16 (linear)
  u16* BlW = Bl + wv*2048 + lane*8;
  const u16* a_base = Al + (wr*64+fr)*64;
  const u16* b_base = Bl + (wc*64+fr)*64;
  int swr = fr & 7;
  for (int k0=0;k0<K;k0+=64){
    #pragma unroll
    for (int i=0;i<4;i++){
      gload16(ApL + k0 + (size_t)i*8*K, AlW + i*512);
      gload16(BpL + k0 + (size_t)i*8*K, BlW + i*512);
    }
    __syncthreads();                      // drains vmcnt -> tile resident
    #pragma unroll
    for (int ks=0;ks<2;ks++){
      int soff = (((ks*4+fg) ^ swr) << 3);
      s16x8 a[4], b[4];
      #pragma unroll
      for (int mi=0;mi<4;mi++) a[mi] = *(const s16x8*)(a_base + mi*1024 + soff);
      #pragma unroll
      for (int ni=0;ni<4;ni++) b[ni] = *(const s16x8*)(b_base + ni*1024 + soff);
      #pragma unroll
      for (int mi=0;mi<4;mi++)
      #pragma unroll
      for (int ni=0;ni<4;ni++)
        acc[mi][ni] = __builtin_amdgcn_mfma_f32_16x16x32_bf16(a[mi], b[ni], acc[mi][ni], 0,0,0);
    }
    __syncthreads();                      // all reads done before next overwrite
  }
  if (EPI==0 || EPI==1){
    #pragma unroll
    for (int mi=0;mi<4;mi++)
    #pragma unroll
    for (int ni=0;ni<4;ni++){
      int c = n0 + wc*64 + ni*16 + fr;
      float bi = bias[c];
      int mb = m0 + wr*64 + mi*16 + fg*4;
      #pragma unroll
      for (int j=0;j<4;j++){
        float vv = acc[mi][ni][j] + bi;
        if (EPI==1) vv = gelu_f(vv);
        outB[(size_t)(mb+j)*Nout + c] = f2bf(vv);
      }
    }
  } else {
    #pragma unroll
    for (int mi=0;mi<4;mi++)
    #pragma unroll
    for (int ni=0;ni<4;ni++){
      int c = n0 + wc*64 + ni*16 + fr;
      float bi = bias[c];
      size_t idx = (size_t)c*M + m0 + wr*64 + mi*16 + fg*4;
      fx4 r4 = *(const fx4*)(res + idx);
      fx4 o;
      #pragma unroll
      for (int j=0;j<4;j++) o[j] = acc[mi][ni][j] + bi + r4[j];
      *(fx4*)(outF + idx) = o;
    }
  }
}

// ---------------- RoPE + gather-into-sorted-window layout ----------------
__global__ __launch_bounds__(256) void rope_kernel(const u16* __restrict__ qkv, const int* __restrict__ order,
    const int* __restrict__ gridO, u16* __restrict__ Qp, u16* __restrict__ Kp, u16* __restrict__ Vp, int N)
{
  __shared__ float csm[64][24][2];
  __shared__ int origs[64];
  int i0 = blockIdx.x<<6;
  int t = threadIdx.x;
  if (t<64) origs[t] = order[i0+t];
  __syncthreads();
  for (int idx=t; idx<64*24; idx+=256){
    int tok = idx/24, slot = idx - tok*24;
    int a = slot>>3, fi = slot&7;
    int pos = gridO[(size_t)origs[tok]*3 + a];
    pos = pos<0?0:(pos>4095?4095:pos);
    float invf = powf(100.0f, -(float)fi*0.125f);
    float ang = (float)pos * invf;
    csm[tok][slot][0] = cosf(ang);
    csm[tok][slot][1] = sinf(ang);
  }
  __syncthreads();
  int tok = t&63;
  int i = i0 + tok;
  const u16* src = qkv + (size_t)origs[tok]*1152;
  u16x8 zz = {0,0,0,0,0,0,0,0};
  for (int h=t>>6; h<8; h+=4){
    size_t dst = ((size_t)h*N + i)*64;
    #pragma unroll
    for (int a=0;a<3;a++){
      u16x8 qa = *(const u16x8*)(src + h*48 + a*16);
      u16x8 qb = *(const u16x8*)(src + h*48 + a*16 + 8);
      u16x8 ka = *(const u16x8*)(src + 384 + h*48 + a*16);
      u16x8 kb = *(const u16x8*)(src + 384 + h*48 + a*16 + 8);
      u16x8 oqa, oqb, oka, okb;
      #pragma unroll
      for (int j=0;j<8;j++){
        float c0 = csm[tok][a*8+j][0], s0 = csm[tok][a*8+j][1];
        float ql = bf2f(qa[j]), qh = bf2f(qb[j]);
        float kl = bf2f(ka[j]), kh = bf2f(kb[j]);
        oqa[j] = f2bf(ql*c0 - qh*s0);
        oqb[j] = f2bf(qh*c0 + ql*s0);
        oka[j] = f2bf(kl*c0 - kh*s0);
        okb[j] = f2bf(kh*c0 + kl*s0);
      }
      *(u16x8*)(Qp + dst + a*16) = oqa;
      *(u16x8*)(Qp + dst + a*16 + 8) = oqb;
      *(u16x8*)(Kp + dst + a*16) = oka;
      *(u16x8*)(Kp + dst + a*16 + 8) = okb;
      u16x8 va = *(const u16x8*)(src + 768 + h*48 + a*16);
      u16x8 vb = *(const u16x8*)(src + 768 + h*48 + a*16 + 8);
      *(u16x8*)(Vp + dst + a*16) = va;
      *(u16x8*)(Vp + dst + a*16 + 8) = vb;
    }
    *(u16x8*)(Qp + dst + 48) = zz; *(u16x8*)(Qp + dst + 56) = zz;
    *(u16x8*)(Kp + dst + 48) = zz; *(u16x8*)(Kp + dst + 56) = zz;
    *(u16x8*)(Vp + dst + 48) = zz; *(u16x8*)(Vp + dst + 56) = zz;
  }
}

// ---------------- V transpose to (h, w, d64, k1024) ----------------
__global__ __launch_bounds__(256) void vtrans_kernel(const u16* __restrict__ Vp, u16* __restrict__ Vt, int N)
{
  __shared__ u16 tl[64][65];
  int nkb = N>>6;
  int h = blockIdx.x / nkb;
  int k0 = (blockIdx.x % nkb)<<6;
  int t=threadIdx.x;
  #pragma unroll
  for (int p=0;p<16;p++){
    int rr = p*4 + (t>>6);
    tl[rr][t&63] = Vp[((size_t)h*N + k0 + rr)*64 + (t&63)];
  }
  __syncthreads();
  int w = k0>>10; int kw0 = k0 & 1023; int nw = N>>10;
  #pragma unroll
  for (int p=0;p<16;p++){
    int dd = p*4 + (t>>6);
    Vt[(((size_t)h*nw + w)*64 + dd)*1024 + kw0 + (t&63)] = tl[t&63][dd];
  }
}

// ---------------- windowed attention: single-pass online softmax with defer-max ----------------
#define ATTN_SCALE 0.14433756729740643f
#define DEFER_RAW 55.0f            // 8 / ATTN_SCALE (P bounded by e^8, safe in bf16)
#define KSTRIDE 68

__global__ __launch_bounds__(512) void attn3_kernel(const u16* __restrict__ Qp, const u16* __restrict__ Kp,
    const u16* __restrict__ Vt, const int* __restrict__ order, u16* __restrict__ attn, int N, int nw)
{
  __shared__ u16 Kl[64*KSTRIDE];       // [key64][d64] stride 68
  __shared__ u16 Vl[48*KSTRIDE];       // [d48][key64] stride 68
  __shared__ u16 Pl[8][32*KSTRIDE];    // per-wave P [q32][key64] stride 68
  int b = blockIdx.x;
  int qc = b & 3;
  int hw = b >> 2;
  int w = hw % nw, h = hw / nw;
  int t = threadIdx.x, lane = t&63, wv = t>>6;
  int fr = lane & 15, fg = lane >> 4;
  size_t base = ((size_t)h*N + (size_t)w*1024);
  size_t vbase = ((size_t)h*nw + w)*64;
  int q0 = qc*256 + wv*32;
  int srow = t>>3, scol = (t&7)*8;
  const u16* ksrc = Kp + (base + srow)*64 + scol;
  const u16* vsrc = Vt + (vbase + srow)*1024 + scol;
  u16* kdst = Kl + srow*KSTRIDE + scol;
  u16* vdst = Vl + srow*KSTRIDE + scol;
  s16x8 qf[2][2];
  #pragma unroll
  for (int n=0;n<2;n++)
  #pragma unroll
  for (int s=0;s<2;s++)
    qf[n][s] = *(const s16x8*)(Qp + (base + q0 + n*16 + fr)*64 + s*32 + fg*8);

  float m0r = -3.4e38f, m1r = -3.4e38f;
  float ls0 = 0.f, ls1 = 0.f;
  fx4 o00=(fx4){0.f,0.f,0.f,0.f}, o01=o00, o02=o00, o10=o00, o11=o00, o12=o00;
  u16* pl = Pl[wv];
  // prefetch chunk 0 into regs (T14)
  ux4 kreg = *(const ux4*)ksrc;
  ux4 vreg = {0,0,0,0};
  if (t < 384) vreg = *(const ux4*)vsrc;

  for (int c=0;c<16;c++){
    __syncthreads();   // previous compute done reading Kl/Vl
    { ux2 lo; lo[0]=kreg[0]; lo[1]=kreg[1];
      ux2 hi; hi[0]=kreg[2]; hi[1]=kreg[3];
      *(ux2*)kdst = lo; *(ux2*)(kdst+4) = hi; }
    if (t < 384){
      ux2 lo; lo[0]=vreg[0]; lo[1]=vreg[1];
      ux2 hi; hi[0]=vreg[2]; hi[1]=vreg[3];
      *(ux2*)vdst = lo; *(ux2*)(vdst+4) = hi;
    }
    __syncthreads();   // stores visible
    if (c < 15){       // issue next-chunk loads: latency hides under compute
      kreg = *(const ux4*)(ksrc + (size_t)(c+1)*4096);
      if (t < 384) vreg = *(const ux4*)(vsrc + (size_t)(c+1)*64);
    }
    // S^T for this chunk (lane owns q-col fr of blocks 0/1)
    fx4 s0[4], s1[4];
    #pragma unroll
    for (int m=0;m<4;m++){
      s0[m]=(fx4){0.f,0.f,0.f,0.f}; s1[m]=s0[m];
      #pragma unroll
      for (int s=0;s<2;s++){
        s16x8 af = ld_bf8(Kl + (m*16+fr)*KSTRIDE + s*32 + fg*8);
        s0[m] = __builtin_amdgcn_mfma_f32_16x16x32_bf16(af, qf[0][s], s0[m], 0,0,0);
        s1[m] = __builtin_amdgcn_mfma_f32_16x16x32_bf16(af, qf[1][s], s1[m], 0,0,0);
      }
    }
    // chunk max per q
    float pm0 = -3.4e38f, pm1 = -3.4e38f;
    #pragma unroll
    for (int m=0;m<4;m++)
    #pragma unroll
    for (int j=0;j<4;j++){ pm0 = fmaxf(pm0, s0[m][j]); pm1 = fmaxf(pm1, s1[m][j]); }
    pm0 = fmaxf(pm0, __shfl_xor(pm0,16)); pm0 = fmaxf(pm0, __shfl_xor(pm0,32));
    pm1 = fmaxf(pm1, __shfl_xor(pm1,16)); pm1 = fmaxf(pm1, __shfl_xor(pm1,32));
    // defer-max: rescale only when chunk max grows past threshold
    if (!__all((pm0 <= m0r + DEFER_RAW) & (pm1 <= m1r + DEFER_RAW))){
      float nm0 = fmaxf(m0r, pm0), nm1 = fmaxf(m1r, pm1);
      float f0 = __expf((m0r - nm0)*ATTN_SCALE);
      float f1 = __expf((m1r - nm1)*ATTN_SCALE);
      ls0 *= f0; ls1 *= f1;
      m0r = nm0; m1r = nm1;
      #pragma unroll
      for (int j=0;j<4;j++){
        float g0 = __shfl(f0, fg*4+j);
        float g1 = __shfl(f1, fg*4+j);
        o00[j]*=g0; o01[j]*=g0; o02[j]*=g0;
        o10[j]*=g1; o11[j]*=g1; o12[j]*=g1;
      }
    }
    // P = exp(S - m), accumulate row sums, stash transposed into per-wave LDS
    #pragma unroll
    for (int m=0;m<4;m++){
      u16x4 p0, p1;
      #pragma unroll
      for (int j=0;j<4;j++){
        float e0 = __expf((s0[m][j]-m0r)*ATTN_SCALE);
        float e1 = __expf((s1[m][j]-m1r)*ATTN_SCALE);
        ls0 += e0; ls1 += e1;
        p0[j] = f2bf(e0); p1[j] = f2bf(e1);
      }
      *(u16x4*)&pl[(fr)*KSTRIDE + m*16 + fg*4]      = p0;
      *(u16x4*)&pl[(16+fr)*KSTRIDE + m*16 + fg*4]   = p1;
    }
    // PV accumulate
    #pragma unroll
    for (int s=0;s<2;s++){
      s16x8 pa0 = ld_bf8(pl + fr*KSTRIDE + s*32 + fg*8);
      s16x8 pa1 = ld_bf8(pl + (16+fr)*KSTRIDE + s*32 + fg*8);
      s16x8 vb0 = ld_bf8(Vl + fr*KSTRIDE + s*32 + fg*8);
      s16x8 vb1 = ld_bf8(Vl + (16+fr)*KSTRIDE + s*32 + fg*8);
      s16x8 vb2 = ld_bf8(Vl + (32+fr)*KSTRIDE + s*32 + fg*8);
      o00 = __builtin_amdgcn_mfma_f32_16x16x32_bf16(pa0, vb0, o00, 0,0,0);
      o01 = __builtin_amdgcn_mfma_f32_16x16x32_bf16(pa0, vb1, o01, 0,0,0);
      o02 = __builtin_amdgcn_mfma_f32_16x16x32_bf16(pa0, vb2, o02, 0,0,0);
      o10 = __builtin_amdgcn_mfma_f32_16x16x32_bf16(pa1, vb0, o10, 0,0,0);
      o11 = __builtin_amdgcn_mfma_f32_16x16x32_bf16(pa1, vb1, o11, 0,0,0);
      o12 = __builtin_amdgcn_mfma_f32_16x16x32_bf16(pa1, vb2, o12, 0,0,0);
    }
  }
  ls0 += __shfl_xor(ls0,16); ls0 += __shfl_xor(ls0,32);
  ls1 += __shfl_xor(ls1,16); ls1 += __shfl_xor(ls1,32);
  float r0 = 1.0f/ls0, r1 = 1.0f/ls1;
  const int* ord = order + w*1024 + q0;
  #pragma unroll
  for (int j=0;j<4;j++){
    float inv0 = __shfl(r0, fg*4+j);
    float inv1 = __shfl(r1, fg*4+j);
    int orig0 = ord[fg*4+j];
    u16* dst0 = attn + (size_t)orig0*384 + h*48;
    dst0[fr]      = f2bf(o00[j]*inv0);
    dst0[16+fr]   = f2bf(o01[j]*inv0);
    dst0[32+fr]   = f2bf(o02[j]*inv0);
    int orig1 = ord[16 + fg*4+j];
    u16* dst1 = attn + (size_t)orig1*384 + h*48;
    dst1[fr]      = f2bf(o10[j]*inv1);
    dst1[16+fr]   = f2bf(o11[j]*inv1);
    dst1[32+fr]   = f2bf(o12[j]*inv1);
  }
}

extern "C" void kernel_launch(void* const* d_in, const int* in_sizes, int n_in,
                              void* d_out, int out_size, void* d_ws, size_t ws_size,
                              hipStream_t stream)
{
  (void)n_in; (void)out_size; (void)ws_size;
  const float* x     = (const float*)d_in[0];
  const float* xyz   = (const float*)d_in[1];
  const float* ln1_g = (const float*)d_in[2];
  const float* ln1_b = (const float*)d_in[3];
  const float* qkv_w = (const float*)d_in[4];
  const float* qkv_b = (const float*)d_in[5];
  const float* proj_w= (const float*)d_in[6];
  const float* proj_b= (const float*)d_in[7];
  const float* ln2_g = (const float*)d_in[8];
  const float* ln2_b = (const float*)d_in[9];
  const float* ffn_w1= (const float*)d_in[10];
  const float* ffn_b1= (const float*)d_in[11];
  const float* ffn_w2= (const float*)d_in[12];
  const float* ffn_b2= (const float*)d_in[13];
  int N = in_sizes[0]/384;
  int nw = N/1024;
  char* wsp = (char*)d_ws;
  size_t off = 0;
  auto alloc = [&](size_t bytes)->char*{ char* p = wsp + off; off = (off + bytes + 255) & ~(size_t)255; return p; };
  int*  order   = (int*)alloc((size_t)N*4);
  int*  gridO   = (int*)alloc((size_t)N*12);
  u32*  mins    = (u32*)alloc(256);
  u64*  keysA   = (u64*)alloc((size_t)N*8);
  u64*  keysB   = (u64*)alloc((size_t)N*8);
  u16*  qkv_wT  = (u16*)alloc((size_t)1152*384*2);
  u16*  proj_wT = (u16*)alloc((size_t)384*384*2);
  u16*  w1T     = (u16*)alloc((size_t)1536*384*2);
  u16*  w2T     = (u16*)alloc((size_t)384*1536*2);
  u16*  xn      = (u16*)alloc((size_t)N*384*2);
  u16*  qkvb    = (u16*)alloc((size_t)N*1152*2);
  u16*  Qp      = (u16*)alloc((size_t)N*64*8*2);
  u16*  Kp      = (u16*)alloc((size_t)N*64*8*2);
  u16*  Vp      = (u16*)alloc((size_t)N*64*8*2);
  u16*  Vt      = (u16*)alloc((size_t)N*64*8*2);
  float* y1     = (float*)alloc((size_t)N*384*4);   // (C, M) layout
  u16*  attn    = xn;     // xn dead after QKV gemm
  u16*  xn2     = qkvb;   // qkvb dead after rope_kernel
  u16*  mid     = Qp;     // Qp/Kp/Vp contiguous & dead after attention; N*1536*2 == 3*(N*64*8*2)
  float* outF = (float*)d_out;

  // ---- parallel Z-order sort ----
  hipMemsetAsync(mins, 0xFF, 12, stream);
  min3_kernel<<<N/256, 256, 0, stream>>>(xyz, mins, N);
  keys_grid_kernel<<<N/256, 256, 0, stream>>>(xyz, mins, keysA, gridO, N);
  bsort_kernel<<<N/2048, 1024, 0, stream>>>(keysA);
  merge_kernel<false><<<N/2048, 256, 0, stream>>>(keysA, keysB, order, 2048, N);
  merge_kernel<false><<<N/2048, 256, 0, stream>>>(keysB, keysA, order, 4096, N);
  merge_kernel<true><<<N/2048, 256, 0, stream>>>(keysA, keysB, order, 8192, N);

  wtrans4_kernel<<<1728, 256, 0, stream>>>(qkv_w, proj_w, ffn_w1, ffn_w2, qkv_wT, proj_wT, w1T, w2T);
  ln32_kernel<<<N/32, 256, 32*388*4, stream>>>(x, ln1_g, ln1_b, xn, N);
  gemm128_kernel<0><<<(N/128)*(1152/128), 256, 0, stream>>>(xn, qkv_wT, qkv_b, qkvb, nullptr, nullptr, N, 1152, 384);
  rope_kernel<<<N/64, 256, 0, stream>>>(qkvb, order, gridO, Qp, Kp, Vp, N);
  vtrans_kernel<<<8*(N/64), 256, 0, stream>>>(Vp, Vt, N);
  attn3_kernel<<<8*nw*4, 512, 0, stream>>>(Qp, Kp, Vt, order, attn, N, nw);
  // proj: y1 (C,M) = x + (attn @ proj_w + b)^T
  gemm128_kernel<2><<<(N/128)*(384/128), 256, 0, stream>>>(attn, proj_wT, proj_b, nullptr, y1, x, N, 384, 384);
  // LN2 = same column-layout LN+transpose as LN1
  ln32_kernel<<<N/32, 256, 32*388*4, stream>>>(y1, ln2_g, ln2_b, xn2, N);
  gemm128_kernel<1><<<(N/128)*(1536/128), 256, 0, stream>>>(xn2, w1T, ffn_b1, mid, nullptr, nullptr, N, 1536, 384);
  // FFN2: d_out (C,M) = y1 + (mid @ w2 + b2)^T
  gemm128_kernel<2><<<(N/128)*(384/128), 256, 0, stream>>>(mid, w2T, ffn_b2, nullptr, outF, y1, N, 384, 1536);
}